// Round 7
// baseline (435.971 us; speedup 1.0000x reference)
//
#include <hip/hip_runtime.h>
#include <hip/hip_bf16.h>
#include <math.h>

#define BB 8
#define NN 4096
#define KNN 20
#define CH 64
#define SAMPLES (BB*NN*KNN)   /* 655360 */
#define EPSF 1e-5f
#define SLOPE 0.2f

typedef float v2f __attribute__((ext_vector_type(2)));

/* decode order-preserving uint back to float */
__device__ __forceinline__ float key_decode(unsigned e) {
    return __uint_as_float((e & 0x80000000u) ? (e ^ 0x80000000u) : ~e);
}

/* rank-select flush: merge ovf[0..cnt) + inc[0..19] -> new exact top-20 in inc. */
__device__ __forceinline__ void rank_flush(unsigned long long* ovf,
                                           unsigned long long* inc,
                                           unsigned long long* scr,
                                           int& cnt, float& kthd, int lane) {
    while (cnt > 0) {
        int take = cnt < 44 ? cnt : 44;
        unsigned long long key;
        if (lane < take)      key = ovf[cnt - take + lane];
        else if (lane >= 44)  key = inc[lane - 44];
        else                  key = ~0ull;
        scr[lane] = key;
        __builtin_amdgcn_wave_barrier();
        int r = 0;
#pragma unroll
        for (int t = 0; t < 64; ++t) {
            unsigned long long kt = scr[t];       /* uniform addr -> broadcast */
            r += (kt < key) ? 1 : 0;
        }
        __builtin_amdgcn_wave_barrier();
        if (r < KNN) inc[r] = key;                /* padding ranks land >= 20 */
        __builtin_amdgcn_wave_barrier();
        kthd = key_decode((unsigned)(inc[KNN-1] >> 32));
        cnt -= take;
    }
}

/* ---------------- K0: precompute (x,y,z,sq) per point (exact ref op order) ----- */
__global__ void pts4_kernel(const float* __restrict__ x, float4* __restrict__ pts4) {
#pragma clang fp contract(off)
    int t = blockIdx.x * 256 + threadIdx.x;       /* 32768 points */
    int b = t >> 12;
    int n = t & (NN - 1);
    const float* xb = x + (size_t)b * 3 * NN;
    float mx = xb[n], my = xb[NN + n], mz = xb[2*NN + n];
    float sq = mx*mx; sq += my*my; sq += mz*mz;   /* ref summation order */
    pts4[t] = make_float4(mx, my, mz, sq);
}

/* ---------------- K1: exact KNN. One wave/query; direct global reads (L1/L2-hot),
   no __syncthreads, register prefetch; exact top-20 set via rank-select. -------- */
__global__ __launch_bounds__(256) void knn_kernel(const float4* __restrict__ pts4,
                                                  int* __restrict__ idx_out) {
#pragma clang fp contract(off)
    __shared__ unsigned long long wb[4][224];                /* 7 KB */
    const int tid = threadIdx.x;
    const int lane = tid & 63;
    const int wv = __builtin_amdgcn_readfirstlane(tid >> 6);
    const int q = blockIdx.x * 4 + wv;                       /* one query/wave */
    const int b = q >> 12;
    const int n = q & (NN - 1);
    const float4* base = pts4 + ((size_t)b << 12);

    unsigned long long* ovf = &wb[wv][0];                    /* 0..127  overflow  */
    unsigned long long* inc = &wb[wv][128];                  /* 128..147 top-20   */
    unsigned long long* scr = &wb[wv][160];                  /* 160..223 scratch  */

    const float4 Q = base[n];                                /* Q.w = sqn */
    float kthd;
    int cnt = 0;

    /* j == 0 batch: rank-select the first 64 candidates directly */
    {
        const float4 P = base[lane];
        float inner = Q.x*P.x; inner += Q.y*P.y; inner += Q.z*P.z;
        const float d = (Q.w - 2.0f*inner) + P.w;
        unsigned uu = __float_as_uint(d);
        unsigned e = uu ^ (((unsigned)((int)uu >> 31)) | 0x80000000u);
        unsigned long long key = ((unsigned long long)e << 32) | (unsigned)lane;
        scr[lane] = key;
        __builtin_amdgcn_wave_barrier();
        int r = 0;
#pragma unroll
        for (int t = 0; t < 64; ++t) {
            unsigned long long kt = scr[t];
            r += (kt < key) ? 1 : 0;
        }
        __builtin_amdgcn_wave_barrier();
        if (r < KNN) inc[r] = key;
        __builtin_amdgcn_wave_barrier();
        kthd = key_decode((unsigned)(inc[KNN-1] >> 32));
    }

    float4 Pn = base[64 + lane];                             /* prefetch j=1 */
    for (int j = 1; j < 64; ++j) {
        const float4 P = Pn;
        if (j < 63) Pn = base[((j + 1) << 6) + lane];        /* prefetch next */
        if (cnt > 64) rank_flush(ovf, inc, scr, cnt, kthd, lane);
        const int m = (j << 6) | lane;
        float inner = Q.x*P.x; inner += Q.y*P.y; inner += Q.z*P.z;
        const float d = (Q.w - 2.0f*inner) + P.w;            /* bitwise same as R6 */
        bool push = d <= kthd;                               /* <=: keep exact ties */
        unsigned long long mask = __ballot(push);
        if (mask) {
            if (push) {
                unsigned uu = __float_as_uint(d);
                unsigned e = uu ^ (((unsigned)((int)uu >> 31)) | 0x80000000u);
                unsigned long long key = ((unsigned long long)e << 32) | (unsigned)m;
                int ofs = (int)__popcll(mask & ((1ull << lane) - 1ull));
                ovf[cnt + ofs] = key;
            }
            cnt += (int)__popcll(mask);
        }
    }
    rank_flush(ovf, inc, scr, cnt, kthd, lane);
    if (lane < KNN)
        idx_out[(size_t)q * KNN + lane] = (int)(unsigned)(inc[lane] & 0xFFFFFFFFull);
}

/* ---------------- K2: per-point projections u,v ------------------------------- */
__global__ void uv_kernel(const float* __restrict__ x, const float* __restrict__ W1,
                          float* __restrict__ u, float* __restrict__ v) {
    int t = blockIdx.x * 256 + threadIdx.x;       /* t = ((b*N+n)<<6)+o */
    int o = t & 63;
    int n = (t >> 6) & (NN - 1);
    int b = t >> 18;
    float X = x[(b*3 + 0)*NN + n];
    float Y = x[(b*3 + 1)*NN + n];
    float Z = x[(b*3 + 2)*NN + n];
    float w0 = W1[o*6+0], w1 = W1[o*6+1], w2 = W1[o*6+2];
    float w3 = W1[o*6+3], w4 = W1[o*6+4], w5 = W1[o*6+5];
    u[t] = w0*X + w1*Y + w2*Z;
    v[t] = (w3 - w0)*X + (w4 - w1)*Y + (w5 - w2)*Z;
}

/* ---------------- K3: bn1 via point moments (h1 is linear in p!) ---------------
   mom[0..2]=A=Σpsum  [3..5]=P1=Σp  [6..11]=M1=Σp_nbr⊗p_nbr (sym)
   [12..20]=M2[i*3+j]=Σpsum_i·p_j   [21..26]=Mpp=Σp⊗p (sym)                     */
__global__ __launch_bounds__(256) void moments_kernel(const float4* __restrict__ pts4,
        const int* __restrict__ idxb, double* __restrict__ mstats) {
    const int t = blockIdx.x * 256 + threadIdx.x;            /* one point/thread */
    const int b = t >> 12;
    const float4* base = pts4 + ((size_t)b << 12);
    const float4 p = base[t & (NN - 1)];
    const int* irow = idxb + (size_t)t * KNN;
    float sx = 0.f, sy = 0.f, sz = 0.f;
    float m1[6] = {0.f,0.f,0.f,0.f,0.f,0.f};
    for (int k = 0; k < KNN; ++k) {
        float4 pn = base[irow[k]];
        sx += pn.x; sy += pn.y; sz += pn.z;
        m1[0] = fmaf(pn.x, pn.x, m1[0]); m1[1] = fmaf(pn.x, pn.y, m1[1]);
        m1[2] = fmaf(pn.x, pn.z, m1[2]); m1[3] = fmaf(pn.y, pn.y, m1[3]);
        m1[4] = fmaf(pn.y, pn.z, m1[4]); m1[5] = fmaf(pn.z, pn.z, m1[5]);
    }
    float mom[27] = {
        sx, sy, sz,  p.x, p.y, p.z,
        m1[0], m1[1], m1[2], m1[3], m1[4], m1[5],
        sx*p.x, sx*p.y, sx*p.z,  sy*p.x, sy*p.y, sy*p.z,  sz*p.x, sz*p.y, sz*p.z,
        p.x*p.x, p.x*p.y, p.x*p.z, p.y*p.y, p.y*p.z, p.z*p.z };
#pragma unroll
    for (int i = 0; i < 27; ++i) {
        float vsum = mom[i];
#pragma unroll
        for (int off = 32; off > 0; off >>= 1) vsum += __shfl_xor(vsum, off);
        if ((threadIdx.x & 63) == 0) atomicAdd(&mstats[i], (double)vsum);
    }
}

/* ---------------- K4: finalize bn1 -> affine from moments ---------------------- */
__global__ void fin1m_kernel(const double* __restrict__ ms, const float* __restrict__ W1,
                             const float* __restrict__ gamma, const float* __restrict__ beta,
                             float* __restrict__ ab) {
    int c = threadIdx.x;
    double wu[3], wv[3];
#pragma unroll
    for (int i = 0; i < 3; ++i) {
        wu[i] = (double)W1[c*6 + i];
        wv[i] = (double)W1[c*6 + 3 + i] - wu[i];
    }
    const double S = (double)SAMPLES;
    double mean = (wu[0]*ms[0] + wu[1]*ms[1] + wu[2]*ms[2]
                 + 20.0*(wv[0]*ms[3] + wv[1]*ms[4] + wv[2]*ms[5])) / S;
    double qM1 = wu[0]*wu[0]*ms[6] + wu[1]*wu[1]*ms[9] + wu[2]*wu[2]*ms[11]
               + 2.0*(wu[0]*wu[1]*ms[7] + wu[0]*wu[2]*ms[8] + wu[1]*wu[2]*ms[10]);
    double cross = 0.0;
#pragma unroll
    for (int i = 0; i < 3; ++i)
#pragma unroll
        for (int j = 0; j < 3; ++j)
            cross += wu[i] * ms[12 + i*3 + j] * wv[j];
    double qpp = wv[0]*wv[0]*ms[21] + wv[1]*wv[1]*ms[24] + wv[2]*wv[2]*ms[26]
               + 2.0*(wv[0]*wv[1]*ms[22] + wv[0]*wv[2]*ms[23] + wv[1]*wv[2]*ms[25]);
    double e2 = (qM1 + 2.0*cross + 20.0*qpp) / S;
    double var = e2 - mean*mean;
    float a = (float)((double)gamma[c] / sqrt(var + (double)EPSF));
    ab[c] = a;
    ab[64 + c] = beta[c] - a * (float)mean;
}

/* ---------------- K6: finalize bn2 -> affine a,b (from raw sums) --------------- */
__global__ void fin_kernel(const double* __restrict__ stats, const float* __restrict__ gamma,
                           const float* __restrict__ beta, float* __restrict__ ab) {
    int o = threadIdx.x;
    double cnt = (double)SAMPLES;
    double mean = stats[o] / cnt;
    double var  = stats[64 + o] / cnt - mean*mean;
    float a = (float)((double)gamma[o] / sqrt(var + (double)EPSF));
    ab[o] = a;
    ab[64 + o] = beta[o] - a * (float)mean;
}

/* ---------------- K5: main pass. lane=channel; 2 points/wave via v_pk_fma_f32;
   1-iteration software pipeline on k (prefetch u, double-buffered g in LDS). ---- */
__global__ __launch_bounds__(256) void main_kernel(const int* __restrict__ idxb,
        const float* __restrict__ u, const float* __restrict__ v,
        const float* __restrict__ ab1, const float* __restrict__ W2,
        float* __restrict__ maxbuf, double* __restrict__ stats2) {
    __shared__ float w2s[64*65];
    __shared__ __align__(16) v2f gbuf[4][2][64];  /* wave, dbuf, channel */
    __shared__ float rsum[4][64], rsq[4][64];
    const int tid = threadIdx.x;
    const int lane = tid & 63;
    const int wv = __builtin_amdgcn_readfirstlane(tid >> 6);
    for (int i = tid; i < 4096; i += 256)
        w2s[(i >> 6)*65 + (i & 63)] = W2[i];
    __syncthreads();
    v2f wp[32];                                   /* W2 row `lane` as 32 pairs */
#pragma unroll
    for (int c2 = 0; c2 < 32; ++c2) {
        wp[c2].x = w2s[lane*65 + 2*c2];
        wp[c2].y = w2s[lane*65 + 2*c2 + 1];
    }
    const float a1 = ab1[lane], b1 = ab1[64 + lane];
    v2f ssum; ssum.x = 0.f; ssum.y = 0.f;
    v2f ssq;  ssq.x  = 0.f; ssq.y  = 0.f;

    const int pt0 = (blockIdx.x * 4 + wv) * 4;    /* 4 points per wave (2 pairs) */
    const int b = pt0 >> 12;
    const float* ub = u + (((size_t)b << 12) << 6);

    for (int pp = 0; pp < 2; ++pp) {
        const int ptA = pt0 + 2*pp, ptB = ptA + 1;
        const float vcA = v[((size_t)ptA << 6) + lane];
        const float vcB = v[((size_t)ptB << 6) + lane];
        const int* irA = idxb + (size_t)ptA * KNN;            /* uniform -> s_load */
        const int* irB = idxb + (size_t)ptB * KNN;
        v2f pmax; pmax.x = -3.4e38f; pmax.y = -3.4e38f;

        /* prologue: g for k=0 into buffer 0 */
        {
            float uA = ub[((size_t)irA[0] << 6) + lane];
            float uB = ub[((size_t)irB[0] << 6) + lane];
            float gA = a1 * (uA + vcA) + b1; gA = fmaxf(gA, SLOPE * gA);
            float gB = a1 * (uB + vcB) + b1; gB = fmaxf(gB, SLOPE * gB);
            v2f g; g.x = gA; g.y = gB;
            gbuf[wv][0][lane] = g;
        }
        for (int k = 0; k < KNN; ++k) {
            float uA, uB;
            if (k < KNN-1) {                       /* prefetch next u pair */
                uA = ub[((size_t)irA[k+1] << 6) + lane];
                uB = ub[((size_t)irB[k+1] << 6) + lane];
            }
            const float4* gp = (const float4*)&gbuf[wv][k & 1][0];
            v2f acc0; acc0.x = 0.f; acc0.y = 0.f;
            v2f acc1; acc1.x = 0.f; acc1.y = 0.f;
#pragma unroll
            for (int c2 = 0; c2 < 32; ++c2) {
                float4 qq = gp[c2];                /* {gA[2c2],gB[2c2],gA[2c2+1],gB[2c2+1]} */
                v2f qa; qa.x = qq.x; qa.y = qq.y;
                v2f qb; qb.x = qq.z; qb.y = qq.w;
                asm("v_pk_fma_f32 %0, %1, %2, %0 op_sel_hi:[1,0,1]"
                    : "+v"(acc0) : "v"(qa), "v"(wp[c2]));
                asm("v_pk_fma_f32 %0, %1, %2, %0 op_sel:[0,1,0] op_sel_hi:[1,1,1]"
                    : "+v"(acc1) : "v"(qb), "v"(wp[c2]));
            }
            if (k < KNN-1) {                       /* stage g for k+1 */
                float gA = a1 * (uA + vcA) + b1; gA = fmaxf(gA, SLOPE * gA);
                float gB = a1 * (uB + vcB) + b1; gB = fmaxf(gB, SLOPE * gB);
                v2f g; g.x = gA; g.y = gB;
                gbuf[wv][(k + 1) & 1][lane] = g;
            }
            v2f h; h.x = acc0.x + acc1.x; h.y = acc0.y + acc1.y;
            pmax.x = fmaxf(pmax.x, h.x); pmax.y = fmaxf(pmax.y, h.y);
            ssum.x += h.x; ssum.y += h.y;
            ssq.x = fmaf(h.x, h.x, ssq.x); ssq.y = fmaf(h.y, h.y, ssq.y);
        }
        maxbuf[((size_t)ptA << 6) + lane] = pmax.x;           /* (b,n,o) coalesced */
        maxbuf[((size_t)ptB << 6) + lane] = pmax.y;
    }
    rsum[wv][lane] = ssum.x + ssum.y; rsq[wv][lane] = ssq.x + ssq.y;
    __syncthreads();
    if (tid < 64) {
        float ts = rsum[0][lane]+rsum[1][lane]+rsum[2][lane]+rsum[3][lane];
        float tq = rsq[0][lane]+rsq[1][lane]+rsq[2][lane]+rsq[3][lane];
        atomicAdd(&stats2[lane], (double)ts);
        atomicAdd(&stats2[64 + lane], (double)tq);
    }
}

/* ---------------- K7: epilogue — transpose (b,n,o)->(b,o,n) + bn2 + lrelu ------ */
__global__ __launch_bounds__(256) void out_kernel(const float* __restrict__ maxbuf,
        const float* __restrict__ ab2, float* __restrict__ out) {
    __shared__ float t[64][65];
    const int tid = threadIdx.x;
    const int b = blockIdx.x >> 6;
    const int n0 = (blockIdx.x & 63) << 6;
#pragma unroll
    for (int i = 0; i < 16; ++i) {
        int r = (tid >> 6) + i*4;                 /* n-row */
        int c = tid & 63;                         /* channel */
        t[r][c] = maxbuf[(((size_t)((b << 12) + n0 + r)) << 6) + c];
    }
    __syncthreads();
#pragma unroll
    for (int i = 0; i < 16; ++i) {
        int o = (tid >> 6) + i*4;
        int nn = tid & 63;
        float a = ab2[o], bb = ab2[64 + o];
        float h = a * t[nn][o] + bb;
        out[(((size_t)(b*64 + o)) << 12) + n0 + nn] = h >= 0.f ? h : SLOPE*h;
    }
}

extern "C" void kernel_launch(void* const* d_in, const int* in_sizes, int n_in,
                              void* d_out, int out_size, void* d_ws, size_t ws_size,
                              hipStream_t stream) {
    const float* x      = (const float*)d_in[0];
    const float* W1     = (const float*)d_in[1];
    const float* gamma1 = (const float*)d_in[2];
    const float* beta1  = (const float*)d_in[3];
    const float* W2     = (const float*)d_in[4];
    const float* gamma2 = (const float*)d_in[5];
    const float* beta2  = (const float*)d_in[6];
    float* out = (float*)d_out;

    char* ws = (char*)d_ws;
    int*    idxb   = (int*)   (ws + 0);           /* 2,621,440 B */
    float*  u      = (float*) (ws + 2621440);     /* 8,388,608 B */
    float*  v      = (float*) (ws + 11010048);    /* 8,388,608 B */
    float*  maxbuf = (float*) (ws + 19398656);    /* 8,388,608 B, layout (b,n,o) */
    float4* pts4   = (float4*)(ws + 19398656);    /* 512 KB, aliases maxbuf:
                                                     dead before main_kernel writes */
    double* mstats = (double*)(ws + 27787264);    /* 27 doubles (bn1 moments) */
    double* stats2 = (double*)(ws + 27788288);    /* 1 KB */
    float*  ab1    = (float*) (ws + 27789312);    /* 512 B */
    float*  ab2    = (float*) (ws + 27789824);    /* 512 B */

    hipMemsetAsync(mstats, 0, 2048, stream);      /* zero mstats+stats2 */

    pts4_kernel   <<<128, 256, 0, stream>>>(x, pts4);
    knn_kernel    <<<8192, 256, 0, stream>>>(pts4, idxb);
    uv_kernel     <<<8192, 256, 0, stream>>>(x, W1, u, v);
    moments_kernel<<<128, 256, 0, stream>>>(pts4, idxb, mstats);
    fin1m_kernel  <<<1, 64, 0, stream>>>(mstats, W1, gamma1, beta1, ab1);
    main_kernel   <<<2048, 256, 0, stream>>>(idxb, u, v, ab1, W2, maxbuf, stats2);
    fin_kernel    <<<1, 64, 0, stream>>>(stats2, gamma2, beta2, ab2);
    out_kernel    <<<512, 256, 0, stream>>>(maxbuf, ab2, out);
}

// Round 8
// 354.923 us; speedup vs baseline: 1.2284x; 1.2284x over previous
//
#include <hip/hip_runtime.h>
#include <hip/hip_bf16.h>
#include <math.h>

#define BB 8
#define NN 4096
#define KNN 20
#define CH 64
#define SAMPLES (BB*NN*KNN)   /* 655360 */
#define EPSF 1e-5f
#define SLOPE 0.2f

typedef float f32x4 __attribute__((ext_vector_type(4)));
typedef short bf16x8 __attribute__((ext_vector_type(8)));

/* decode order-preserving uint back to float */
__device__ __forceinline__ float key_decode(unsigned e) {
    return __uint_as_float((e & 0x80000000u) ? (e ^ 0x80000000u) : ~e);
}

/* rank-select flush: merge ovf[0..cnt) + inc[0..19] -> new exact top-20 in inc. */
__device__ __forceinline__ void rank_flush(unsigned long long* ovf,
                                           unsigned long long* inc,
                                           unsigned long long* scr,
                                           int& cnt, float& kthd, int lane) {
    while (cnt > 0) {
        int take = cnt < 44 ? cnt : 44;
        unsigned long long key;
        if (lane < take)      key = ovf[cnt - take + lane];
        else if (lane >= 44)  key = inc[lane - 44];
        else                  key = ~0ull;
        scr[lane] = key;
        __builtin_amdgcn_wave_barrier();
        int r = 0;
#pragma unroll
        for (int t = 0; t < 64; ++t) {
            unsigned long long kt = scr[t];       /* uniform addr -> broadcast */
            r += (kt < key) ? 1 : 0;
        }
        __builtin_amdgcn_wave_barrier();
        if (r < KNN) inc[r] = key;                /* padding ranks land >= 20 */
        __builtin_amdgcn_wave_barrier();
        kthd = key_decode((unsigned)(inc[KNN-1] >> 32));
        cnt -= take;
    }
}

/* ---------------- K0: precompute (x,y,z,sq) per point (exact ref op order) ----- */
__global__ void pts4_kernel(const float* __restrict__ x, float4* __restrict__ pts4) {
#pragma clang fp contract(off)
    int t = blockIdx.x * 256 + threadIdx.x;       /* 32768 points */
    int b = t >> 12;
    int n = t & (NN - 1);
    const float* xb = x + (size_t)b * 3 * NN;
    float mx = xb[n], my = xb[NN + n], mz = xb[2*NN + n];
    float sq = mx*mx; sq += my*my; sq += mz*mz;   /* ref summation order */
    pts4[t] = make_float4(mx, my, mz, sq);
}

/* ---------------- K1: exact KNN (R7 version, unchanged) ------------------------ */
__global__ __launch_bounds__(256) void knn_kernel(const float4* __restrict__ pts4,
                                                  int* __restrict__ idx_out) {
#pragma clang fp contract(off)
    __shared__ unsigned long long wb[4][224];                /* 7 KB */
    const int tid = threadIdx.x;
    const int lane = tid & 63;
    const int wv = __builtin_amdgcn_readfirstlane(tid >> 6);
    const int q = blockIdx.x * 4 + wv;                       /* one query/wave */
    const int b = q >> 12;
    const int n = q & (NN - 1);
    const float4* base = pts4 + ((size_t)b << 12);

    unsigned long long* ovf = &wb[wv][0];
    unsigned long long* inc = &wb[wv][128];
    unsigned long long* scr = &wb[wv][160];

    const float4 Q = base[n];                                /* Q.w = sqn */
    float kthd;
    int cnt = 0;

    {
        const float4 P = base[lane];
        float inner = Q.x*P.x; inner += Q.y*P.y; inner += Q.z*P.z;
        const float d = (Q.w - 2.0f*inner) + P.w;
        unsigned uu = __float_as_uint(d);
        unsigned e = uu ^ (((unsigned)((int)uu >> 31)) | 0x80000000u);
        unsigned long long key = ((unsigned long long)e << 32) | (unsigned)lane;
        scr[lane] = key;
        __builtin_amdgcn_wave_barrier();
        int r = 0;
#pragma unroll
        for (int t = 0; t < 64; ++t) {
            unsigned long long kt = scr[t];
            r += (kt < key) ? 1 : 0;
        }
        __builtin_amdgcn_wave_barrier();
        if (r < KNN) inc[r] = key;
        __builtin_amdgcn_wave_barrier();
        kthd = key_decode((unsigned)(inc[KNN-1] >> 32));
    }

    float4 Pn = base[64 + lane];
    for (int j = 1; j < 64; ++j) {
        const float4 P = Pn;
        if (j < 63) Pn = base[((j + 1) << 6) + lane];
        if (cnt > 64) rank_flush(ovf, inc, scr, cnt, kthd, lane);
        const int m = (j << 6) | lane;
        float inner = Q.x*P.x; inner += Q.y*P.y; inner += Q.z*P.z;
        const float d = (Q.w - 2.0f*inner) + P.w;
        bool push = d <= kthd;
        unsigned long long mask = __ballot(push);
        if (mask) {
            if (push) {
                unsigned uu = __float_as_uint(d);
                unsigned e = uu ^ (((unsigned)((int)uu >> 31)) | 0x80000000u);
                unsigned long long key = ((unsigned long long)e << 32) | (unsigned)m;
                int ofs = (int)__popcll(mask & ((1ull << lane) - 1ull));
                ovf[cnt + ofs] = key;
            }
            cnt += (int)__popcll(mask);
        }
    }
    rank_flush(ovf, inc, scr, cnt, kthd, lane);
    if (lane < KNN)
        idx_out[(size_t)q * KNN + lane] = (int)(unsigned)(inc[lane] & 0xFFFFFFFFull);
}

/* ---------------- K2: per-point projections u,v ------------------------------- */
__global__ void uv_kernel(const float* __restrict__ x, const float* __restrict__ W1,
                          float* __restrict__ u, float* __restrict__ v) {
    int t = blockIdx.x * 256 + threadIdx.x;       /* t = ((b*N+n)<<6)+o */
    int o = t & 63;
    int n = (t >> 6) & (NN - 1);
    int b = t >> 18;
    float X = x[(b*3 + 0)*NN + n];
    float Y = x[(b*3 + 1)*NN + n];
    float Z = x[(b*3 + 2)*NN + n];
    float w0 = W1[o*6+0], w1 = W1[o*6+1], w2 = W1[o*6+2];
    float w3 = W1[o*6+3], w4 = W1[o*6+4], w5 = W1[o*6+5];
    u[t] = w0*X + w1*Y + w2*Z;
    v[t] = (w3 - w0)*X + (w4 - w1)*Y + (w5 - w2)*Z;
}

/* ---------------- K3: bn1 via point moments (h1 linear in p) ------------------- */
__global__ __launch_bounds__(256) void moments_kernel(const float4* __restrict__ pts4,
        const int* __restrict__ idxb, double* __restrict__ mstats) {
    const int t = blockIdx.x * 256 + threadIdx.x;
    const int b = t >> 12;
    const float4* base = pts4 + ((size_t)b << 12);
    const float4 p = base[t & (NN - 1)];
    const int* irow = idxb + (size_t)t * KNN;
    float sx = 0.f, sy = 0.f, sz = 0.f;
    float m1[6] = {0.f,0.f,0.f,0.f,0.f,0.f};
    for (int k = 0; k < KNN; ++k) {
        float4 pn = base[irow[k]];
        sx += pn.x; sy += pn.y; sz += pn.z;
        m1[0] = fmaf(pn.x, pn.x, m1[0]); m1[1] = fmaf(pn.x, pn.y, m1[1]);
        m1[2] = fmaf(pn.x, pn.z, m1[2]); m1[3] = fmaf(pn.y, pn.y, m1[3]);
        m1[4] = fmaf(pn.y, pn.z, m1[4]); m1[5] = fmaf(pn.z, pn.z, m1[5]);
    }
    float mom[27] = {
        sx, sy, sz,  p.x, p.y, p.z,
        m1[0], m1[1], m1[2], m1[3], m1[4], m1[5],
        sx*p.x, sx*p.y, sx*p.z,  sy*p.x, sy*p.y, sy*p.z,  sz*p.x, sz*p.y, sz*p.z,
        p.x*p.x, p.x*p.y, p.x*p.z, p.y*p.y, p.y*p.z, p.z*p.z };
#pragma unroll
    for (int i = 0; i < 27; ++i) {
        float vsum = mom[i];
#pragma unroll
        for (int off = 32; off > 0; off >>= 1) vsum += __shfl_xor(vsum, off);
        if ((threadIdx.x & 63) == 0) atomicAdd(&mstats[i], (double)vsum);
    }
}

/* ---------------- K4: finalize bn1 -> affine from moments ---------------------- */
__global__ void fin1m_kernel(const double* __restrict__ ms, const float* __restrict__ W1,
                             const float* __restrict__ gamma, const float* __restrict__ beta,
                             float* __restrict__ ab) {
    int c = threadIdx.x;
    double wu[3], wv[3];
#pragma unroll
    for (int i = 0; i < 3; ++i) {
        wu[i] = (double)W1[c*6 + i];
        wv[i] = (double)W1[c*6 + 3 + i] - wu[i];
    }
    const double S = (double)SAMPLES;
    double mean = (wu[0]*ms[0] + wu[1]*ms[1] + wu[2]*ms[2]
                 + 20.0*(wv[0]*ms[3] + wv[1]*ms[4] + wv[2]*ms[5])) / S;
    double qM1 = wu[0]*wu[0]*ms[6] + wu[1]*wu[1]*ms[9] + wu[2]*wu[2]*ms[11]
               + 2.0*(wu[0]*wu[1]*ms[7] + wu[0]*wu[2]*ms[8] + wu[1]*wu[2]*ms[10]);
    double cross = 0.0;
#pragma unroll
    for (int i = 0; i < 3; ++i)
#pragma unroll
        for (int j = 0; j < 3; ++j)
            cross += wu[i] * ms[12 + i*3 + j] * wv[j];
    double qpp = wv[0]*wv[0]*ms[21] + wv[1]*wv[1]*ms[24] + wv[2]*wv[2]*ms[26]
               + 2.0*(wv[0]*wv[1]*ms[22] + wv[0]*wv[2]*ms[23] + wv[1]*wv[2]*ms[25]);
    double e2 = (qM1 + 2.0*cross + 20.0*qpp) / S;
    double var = e2 - mean*mean;
    float a = (float)((double)gamma[c] / sqrt(var + (double)EPSF));
    ab[c] = a;
    ab[64 + c] = beta[c] - a * (float)mean;
}

/* split fp32 -> bf16 hi (truncate) + bf16 lo (truncated remainder) */
__device__ __forceinline__ void bsplit(float g, short& hi, short& lo) {
    unsigned bits = __float_as_uint(g);
    unsigned hbits = bits & 0xFFFF0000u;
    float rem = g - __uint_as_float(hbits);
    hi = (short)(bits >> 16);
    lo = (short)(__float_as_uint(rem) >> 16);
}

/* ---------------- K5: main pass — split-bf16 MFMA GEMM per point ---------------
   Per wave, per point: stage g (20x64) as bf16 hi/lo tiles in LDS, then
   M=20 (16+4pad), N=64, K=64 GEMM via 48 mfma_f32_16x16x32_bf16.
   Max-over-k + bn2 sums reduced in-register from C-layout (rows = k). -------- */
__global__ __launch_bounds__(256) void main_kernel(const int* __restrict__ idxb,
        const float* __restrict__ u, const float* __restrict__ v,
        const float* __restrict__ ab1, const float* __restrict__ W2,
        float* __restrict__ maxbuf, float* __restrict__ stats2f) {
    __shared__ __align__(16) short Thi[4][32*72];  /* 18.4 KB, row stride 72 (pad) */
    __shared__ __align__(16) short Tlo[4][32*72];  /* 18.4 KB */
    __shared__ float chs[128];
    const int tid = threadIdx.x;
    const int lane = tid & 63;
    const int wv = __builtin_amdgcn_readfirstlane(tid >> 6);
    const int l15 = lane & 15;
    const int quad = lane >> 4;
    if (tid < 128) chs[tid] = 0.f;
    __syncthreads();

    /* B-frags: W2 as bf16 hi/lo. B[k=c][n=o]: lane holds k=quad*8+j, n=l15. */
    bf16x8 whi[8], wlo[8];                         /* [t*2+f] */
#pragma unroll
    for (int t = 0; t < 4; ++t)
#pragma unroll
    for (int f = 0; f < 2; ++f) {
        const int o = 16*t + l15;
        const int c0 = 32*f + quad*8;
        const float4* wr = (const float4*)(W2 + o*64 + c0);
        float4 w0 = wr[0], w1 = wr[1];
        float vals[8] = {w0.x,w0.y,w0.z,w0.w,w1.x,w1.y,w1.z,w1.w};
        bf16x8 h, l;
#pragma unroll
        for (int j = 0; j < 8; ++j) { short hj, lj; bsplit(vals[j], hj, lj); h[j]=hj; l[j]=lj; }
        whi[t*2+f] = h; wlo[t*2+f] = l;
    }

    const float a1 = ab1[lane], b1 = ab1[64 + lane];
    float ssum[4] = {0.f,0.f,0.f,0.f}, ssq[4] = {0.f,0.f,0.f,0.f};
    short* thi = &Thi[wv][0];
    short* tlo = &Tlo[wv][0];

    const int pt0 = (blockIdx.x * 4 + wv) * 4;     /* 4 points per wave */
    const int b = pt0 >> 12;
    const float* ub = u + ((size_t)b << 18);

    for (int p = 0; p < 4; ++p) {
        const int pt = pt0 + p;
        const float vc = v[((size_t)pt << 6) + lane];
        const int* irow = idxb + (size_t)pt * KNN;  /* uniform -> s_load */

        /* stage g: lane = channel c; row k = neighbor index */
#pragma unroll
        for (int k = 0; k < KNN; ++k) {
            int nbr = irow[k];
            float uc = ub[((size_t)nbr << 6) + lane];
            float g = a1 * (uc + vc) + b1;
            g = fmaxf(g, SLOPE * g);
            short hj, lj; bsplit(g, hj, lj);
            thi[k*72 + lane] = hj;
            tlo[k*72 + lane] = lj;
        }
        __builtin_amdgcn_wave_barrier();           /* same-wave DS is in-order */

        /* A-frags: A[m][k]: m=l15 (tile1) / 16+l15 (tile2), k=quad*8+j */
        bf16x8 ah1[2], al1[2], ah2[2], al2[2];
#pragma unroll
        for (int f = 0; f < 2; ++f) {
            const int co = 32*f + quad*8;
            ah1[f] = *(const bf16x8*)&thi[l15*72 + co];
            al1[f] = *(const bf16x8*)&tlo[l15*72 + co];
            ah2[f] = *(const bf16x8*)&thi[(16 + l15)*72 + co];
            al2[f] = *(const bf16x8*)&tlo[(16 + l15)*72 + co];
        }

        f32x4 acc1[4], acc2[4];
#pragma unroll
        for (int t = 0; t < 4; ++t) { acc1[t] = (f32x4)0.f; acc2[t] = (f32x4)0.f; }
#pragma unroll
        for (int t = 0; t < 4; ++t) {
#pragma unroll
            for (int f = 0; f < 2; ++f) {
                acc1[t] = __builtin_amdgcn_mfma_f32_16x16x32_bf16(ah1[f], whi[t*2+f], acc1[t], 0,0,0);
                acc1[t] = __builtin_amdgcn_mfma_f32_16x16x32_bf16(al1[f], whi[t*2+f], acc1[t], 0,0,0);
                acc1[t] = __builtin_amdgcn_mfma_f32_16x16x32_bf16(ah1[f], wlo[t*2+f], acc1[t], 0,0,0);
                acc2[t] = __builtin_amdgcn_mfma_f32_16x16x32_bf16(ah2[f], whi[t*2+f], acc2[t], 0,0,0);
                acc2[t] = __builtin_amdgcn_mfma_f32_16x16x32_bf16(al2[f], whi[t*2+f], acc2[t], 0,0,0);
                acc2[t] = __builtin_amdgcn_mfma_f32_16x16x32_bf16(ah2[f], wlo[t*2+f], acc2[t], 0,0,0);
            }
        }
        __builtin_amdgcn_wave_barrier();           /* frag reads done before next p stage */

        /* epilogue: C-layout col=l15(+16t), row=quad*4+reg = k. tile2 valid: quad0 */
        const bool q0 = (quad == 0);
#pragma unroll
        for (int t = 0; t < 4; ++t) {
            float m1 = fmaxf(fmaxf(acc1[t][0], acc1[t][1]), fmaxf(acc1[t][2], acc1[t][3]));
            float s1 = acc1[t][0] + acc1[t][1] + acc1[t][2] + acc1[t][3];
            float q1 = acc1[t][0]*acc1[t][0] + acc1[t][1]*acc1[t][1]
                     + acc1[t][2]*acc1[t][2] + acc1[t][3]*acc1[t][3];
            float m2 = fmaxf(fmaxf(acc2[t][0], acc2[t][1]), fmaxf(acc2[t][2], acc2[t][3]));
            float s2 = acc2[t][0] + acc2[t][1] + acc2[t][2] + acc2[t][3];
            float q2 = acc2[t][0]*acc2[t][0] + acc2[t][1]*acc2[t][1]
                     + acc2[t][2]*acc2[t][2] + acc2[t][3]*acc2[t][3];
            float lm = q0 ? fmaxf(m1, m2) : m1;
            float ls = q0 ? (s1 + s2) : s1;
            float lq = q0 ? (q1 + q2) : q1;
            lm = fmaxf(lm, __shfl_xor(lm, 16)); lm = fmaxf(lm, __shfl_xor(lm, 32));
            ls += __shfl_xor(ls, 16); ls += __shfl_xor(ls, 32);
            lq += __shfl_xor(lq, 16); lq += __shfl_xor(lq, 32);
            if (q0) maxbuf[((size_t)pt << 6) + 16*t + l15] = lm;
            ssum[t] += ls; ssq[t] += lq;
        }
    }

    if (quad == 0) {
#pragma unroll
        for (int t = 0; t < 4; ++t) {
            atomicAdd(&chs[16*t + l15], ssum[t]);
            atomicAdd(&chs[64 + 16*t + l15], ssq[t]);
        }
    }
    __syncthreads();
    if (tid < 128)
        atomicAdd(&stats2f[(blockIdx.x & 1)*128 + tid], chs[tid]);
}

/* ---------------- K6: finalize bn2 -> affine (2-copy float partials) ----------- */
__global__ void fin2_kernel(const float* __restrict__ s2f, const float* __restrict__ gamma,
                            const float* __restrict__ beta, float* __restrict__ ab) {
    int o = threadIdx.x;
    double sum = (double)s2f[o] + (double)s2f[128 + o];
    double sq  = (double)s2f[64 + o] + (double)s2f[192 + o];
    double cnt = (double)SAMPLES;
    double mean = sum / cnt;
    double var  = sq / cnt - mean*mean;
    float a = (float)((double)gamma[o] / sqrt(var + (double)EPSF));
    ab[o] = a;
    ab[64 + o] = beta[o] - a * (float)mean;
}

/* ---------------- K7: epilogue — transpose (b,n,o)->(b,o,n) + bn2 + lrelu ------ */
__global__ __launch_bounds__(256) void out_kernel(const float* __restrict__ maxbuf,
        const float* __restrict__ ab2, float* __restrict__ out) {
    __shared__ float t[64][65];
    const int tid = threadIdx.x;
    const int b = blockIdx.x >> 6;
    const int n0 = (blockIdx.x & 63) << 6;
#pragma unroll
    for (int i = 0; i < 16; ++i) {
        int r = (tid >> 6) + i*4;
        int c = tid & 63;
        t[r][c] = maxbuf[(((size_t)((b << 12) + n0 + r)) << 6) + c];
    }
    __syncthreads();
#pragma unroll
    for (int i = 0; i < 16; ++i) {
        int o = (tid >> 6) + i*4;
        int nn = tid & 63;
        float a = ab2[o], bb = ab2[64 + o];
        float h = a * t[nn][o] + bb;
        out[(((size_t)(b*64 + o)) << 12) + n0 + nn] = h >= 0.f ? h : SLOPE*h;
    }
}

extern "C" void kernel_launch(void* const* d_in, const int* in_sizes, int n_in,
                              void* d_out, int out_size, void* d_ws, size_t ws_size,
                              hipStream_t stream) {
    const float* x      = (const float*)d_in[0];
    const float* W1     = (const float*)d_in[1];
    const float* gamma1 = (const float*)d_in[2];
    const float* beta1  = (const float*)d_in[3];
    const float* W2     = (const float*)d_in[4];
    const float* gamma2 = (const float*)d_in[5];
    const float* beta2  = (const float*)d_in[6];
    float* out = (float*)d_out;

    char* ws = (char*)d_ws;
    int*    idxb    = (int*)   (ws + 0);           /* 2,621,440 B */
    float*  u       = (float*) (ws + 2621440);     /* 8,388,608 B */
    float*  v       = (float*) (ws + 11010048);    /* 8,388,608 B */
    float*  maxbuf  = (float*) (ws + 19398656);    /* 8,388,608 B, (b,n,o) */
    float4* pts4    = (float4*)(ws + 19398656);    /* 512 KB alias (dead pre-main) */
    double* mstats  = (double*)(ws + 27787264);    /* 27 doubles */
    float*  stats2f = (float*) (ws + 27787520);    /* 2x128 floats */
    float*  ab1     = (float*) (ws + 27788544);    /* 512 B */
    float*  ab2     = (float*) (ws + 27789056);    /* 512 B -> ends 27,789,568 */

    hipMemsetAsync(mstats, 0, 1280, stream);       /* zero mstats + stats2f */

    pts4_kernel   <<<128, 256, 0, stream>>>(x, pts4);
    knn_kernel    <<<8192, 256, 0, stream>>>(pts4, idxb);
    uv_kernel     <<<8192, 256, 0, stream>>>(x, W1, u, v);
    moments_kernel<<<128, 256, 0, stream>>>(pts4, idxb, mstats);
    fin1m_kernel  <<<1, 64, 0, stream>>>(mstats, W1, gamma1, beta1, ab1);
    main_kernel   <<<2048, 256, 0, stream>>>(idxb, u, v, ab1, W2, maxbuf, stats2f);
    fin2_kernel   <<<1, 64, 0, stream>>>(stats2f, gamma2, beta2, ab2);
    out_kernel    <<<512, 256, 0, stream>>>(maxbuf, ab2, out);
}

// Round 9
// 345.901 us; speedup vs baseline: 1.2604x; 1.0261x over previous
//
#include <hip/hip_runtime.h>
#include <hip/hip_bf16.h>
#include <math.h>

#define BB 8
#define NN 4096
#define KNN 20
#define CH 64
#define SAMPLES (BB*NN*KNN)   /* 655360 */
#define EPSF 1e-5f
#define SLOPE 0.2f

typedef float f32x4 __attribute__((ext_vector_type(4)));
typedef short bf16x8 __attribute__((ext_vector_type(8)));

/* decode order-preserving uint back to float */
__device__ __forceinline__ float key_decode(unsigned e) {
    return __uint_as_float((e & 0x80000000u) ? (e ^ 0x80000000u) : ~e);
}

/* rank-select flush: merge ovf[0..cnt) + inc[0..19] -> new exact top-20 in inc. */
__device__ __forceinline__ void rank_flush(unsigned long long* ovf,
                                           unsigned long long* inc,
                                           unsigned long long* scr,
                                           int& cnt, float& kthd, int lane) {
    while (cnt > 0) {
        int take = cnt < 44 ? cnt : 44;
        unsigned long long key;
        if (lane < take)      key = ovf[cnt - take + lane];
        else if (lane >= 44)  key = inc[lane - 44];
        else                  key = ~0ull;
        scr[lane] = key;
        __builtin_amdgcn_wave_barrier();
        int r = 0;
#pragma unroll
        for (int t = 0; t < 64; ++t) {
            unsigned long long kt = scr[t];       /* uniform addr -> broadcast */
            r += (kt < key) ? 1 : 0;
        }
        __builtin_amdgcn_wave_barrier();
        if (r < KNN) inc[r] = key;                /* padding ranks land >= 20 */
        __builtin_amdgcn_wave_barrier();
        kthd = key_decode((unsigned)(inc[KNN-1] >> 32));
        cnt -= take;
    }
}

/* ---------------- K0: pts in screen format (-2x,-2y,-2z,sq); zero stats ------- */
__global__ void pts4_kernel(const float* __restrict__ x, float4* __restrict__ pts4,
                            float2* __restrict__ zbuf) {
#pragma clang fp contract(off)
    int t = blockIdx.x * 256 + threadIdx.x;       /* 32768 points */
    if (blockIdx.x == 0 && threadIdx.x < 160)     /* zero mstats+stats2f (1280 B) */
        zbuf[threadIdx.x] = make_float2(0.f, 0.f);
    int b = t >> 12;
    int n = t & (NN - 1);
    const float* xb = x + (size_t)b * 3 * NN;
    float mx = xb[n], my = xb[NN + n], mz = xb[2*NN + n];
    float sq = mx*mx; sq += my*my; sq += mz*mz;   /* ref summation order */
    pts4[t] = make_float4(-2.0f*mx, -2.0f*my, -2.0f*mz, sq);  /* exact scalings */
}

/* ---------------- K1: exact KNN with cheap fma screen + exact keys ------------- */
__global__ __launch_bounds__(256) void knn_kernel(const float4* __restrict__ pts4,
                                                  int* __restrict__ idx_out) {
#pragma clang fp contract(off)
    __shared__ unsigned long long wb[4][224];                /* 7 KB */
    const int tid = threadIdx.x;
    const int lane = tid & 63;
    const int wv = __builtin_amdgcn_readfirstlane(tid >> 6);
    const int q = blockIdx.x * 4 + wv;                       /* one query/wave */
    const int b = q >> 12;
    const int n = q & (NN - 1);
    const float4* base = pts4 + ((size_t)b << 12);

    unsigned long long* ovf = &wb[wv][0];
    unsigned long long* inc = &wb[wv][128];
    unsigned long long* scr = &wb[wv][160];

    const float4 Qc = base[n];
    const float qx = -0.5f*Qc.x, qy = -0.5f*Qc.y, qz = -0.5f*Qc.z; /* exact coords */
    const float sqn = Qc.w;
    float kthd, thr;
    int cnt = 0;

    /* j == 0 batch: exact d for first 64, rank-select directly */
    {
        const float4 P = base[lane];
        const float mx = -0.5f*P.x, my = -0.5f*P.y, mz = -0.5f*P.z;
        float inner = qx*mx; inner += qy*my; inner += qz*mz;
        const float d = (sqn - 2.0f*inner) + P.w;            /* ref parenthesization */
        unsigned uu = __float_as_uint(d);
        unsigned e = uu ^ (((unsigned)((int)uu >> 31)) | 0x80000000u);
        unsigned long long key = ((unsigned long long)e << 32) | (unsigned)lane;
        scr[lane] = key;
        __builtin_amdgcn_wave_barrier();
        int r = 0;
#pragma unroll
        for (int t = 0; t < 64; ++t) {
            unsigned long long kt = scr[t];
            r += (kt < key) ? 1 : 0;
        }
        __builtin_amdgcn_wave_barrier();
        if (r < KNN) inc[r] = key;
        __builtin_amdgcn_wave_barrier();
        kthd = key_decode((unsigned)(inc[KNN-1] >> 32));
        thr = (kthd - sqn) + 1e-3f*(fabsf(kthd) + fabsf(sqn) + 1.0f);
    }

    float4 Pn = base[64 + lane];
    for (int j = 1; j < 64; ++j) {
        const float4 P = Pn;
        if (j < 63) Pn = base[((j + 1) << 6) + lane];
        if (cnt > 64) {
            rank_flush(ovf, inc, scr, cnt, kthd, lane);
            thr = (kthd - sqn) + 1e-3f*(fabsf(kthd) + fabsf(sqn) + 1.0f);
        }
        /* screen: s ~= d - sqn (4 VALU). Conservative: over-push only. */
        const float s = fmaf(P.x, qx, fmaf(P.y, qy, fmaf(P.z, qz, P.w)));
        bool push = s <= thr;
        unsigned long long mask = __ballot(push);
        if (mask) {
            if (push) {                            /* rare: exact bitwise key here */
                const float mx = -0.5f*P.x, my = -0.5f*P.y, mz = -0.5f*P.z;
                float inner = qx*mx; inner += qy*my; inner += qz*mz;
                const float d = (sqn - 2.0f*inner) + P.w;
                unsigned uu = __float_as_uint(d);
                unsigned e = uu ^ (((unsigned)((int)uu >> 31)) | 0x80000000u);
                const int m = (j << 6) | lane;
                unsigned long long key = ((unsigned long long)e << 32) | (unsigned)m;
                int ofs = (int)__popcll(mask & ((1ull << lane) - 1ull));
                ovf[cnt + ofs] = key;
            }
            cnt += (int)__popcll(mask);
        }
    }
    rank_flush(ovf, inc, scr, cnt, kthd, lane);
    if (lane < KNN)
        idx_out[(size_t)q * KNN + lane] = (int)(unsigned)(inc[lane] & 0xFFFFFFFFull);
}

/* ---------------- K2: per-point projections u,v ------------------------------- */
__global__ void uv_kernel(const float* __restrict__ x, const float* __restrict__ W1,
                          float* __restrict__ u, float* __restrict__ v) {
    int t = blockIdx.x * 256 + threadIdx.x;       /* t = ((b*N+n)<<6)+o */
    int o = t & 63;
    int n = (t >> 6) & (NN - 1);
    int b = t >> 18;
    float X = x[(b*3 + 0)*NN + n];
    float Y = x[(b*3 + 1)*NN + n];
    float Z = x[(b*3 + 2)*NN + n];
    float w0 = W1[o*6+0], w1 = W1[o*6+1], w2 = W1[o*6+2];
    float w3 = W1[o*6+3], w4 = W1[o*6+4], w5 = W1[o*6+5];
    u[t] = w0*X + w1*Y + w2*Z;
    v[t] = (w3 - w0)*X + (w4 - w1)*Y + (w5 - w2)*Z;
}

/* ---------------- K3: bn1 via point moments (coords recovered exactly) --------- */
__global__ __launch_bounds__(256) void moments_kernel(const float4* __restrict__ pts4,
        const int* __restrict__ idxb, double* __restrict__ mstats) {
    const int t = blockIdx.x * 256 + threadIdx.x;
    const int b = t >> 12;
    const float4* base = pts4 + ((size_t)b << 12);
    const float4 pc = base[t & (NN - 1)];
    const float px = -0.5f*pc.x, py = -0.5f*pc.y, pz = -0.5f*pc.z;
    const int* irow = idxb + (size_t)t * KNN;
    float sx = 0.f, sy = 0.f, sz = 0.f;
    float m1[6] = {0.f,0.f,0.f,0.f,0.f,0.f};
    for (int k = 0; k < KNN; ++k) {
        float4 pn = base[irow[k]];
        float nx = -0.5f*pn.x, ny = -0.5f*pn.y, nz = -0.5f*pn.z;
        sx += nx; sy += ny; sz += nz;
        m1[0] = fmaf(nx, nx, m1[0]); m1[1] = fmaf(nx, ny, m1[1]);
        m1[2] = fmaf(nx, nz, m1[2]); m1[3] = fmaf(ny, ny, m1[3]);
        m1[4] = fmaf(ny, nz, m1[4]); m1[5] = fmaf(nz, nz, m1[5]);
    }
    float mom[27] = {
        sx, sy, sz,  px, py, pz,
        m1[0], m1[1], m1[2], m1[3], m1[4], m1[5],
        sx*px, sx*py, sx*pz,  sy*px, sy*py, sy*pz,  sz*px, sz*py, sz*pz,
        px*px, px*py, px*pz, py*py, py*pz, pz*pz };
#pragma unroll
    for (int i = 0; i < 27; ++i) {
        float vsum = mom[i];
#pragma unroll
        for (int off = 32; off > 0; off >>= 1) vsum += __shfl_xor(vsum, off);
        if ((threadIdx.x & 63) == 0) atomicAdd(&mstats[i], (double)vsum);
    }
}

/* split fp32 -> bf16 hi (truncate) + bf16 lo (truncated remainder) */
__device__ __forceinline__ void bsplit(float g, short& hi, short& lo) {
    unsigned bits = __float_as_uint(g);
    unsigned hbits = bits & 0xFFFF0000u;
    float rem = g - __uint_as_float(hbits);
    hi = (short)(bits >> 16);
    lo = (short)(__float_as_uint(rem) >> 16);
}

/* ---------------- K5: main pass — split-bf16 MFMA GEMM; fin1 inlined ----------- */
__global__ __launch_bounds__(256) void main_kernel(const int* __restrict__ idxb,
        const float* __restrict__ u, const float* __restrict__ v,
        const double* __restrict__ ms, const float* __restrict__ W1,
        const float* __restrict__ gamma1, const float* __restrict__ beta1,
        const float* __restrict__ W2,
        float* __restrict__ maxbuf, float* __restrict__ stats2f) {
    __shared__ __align__(16) short Thi[4][32*72];
    __shared__ __align__(16) short Tlo[4][32*72];
    __shared__ float chs[128];
    __shared__ float ab1s[128];
    const int tid = threadIdx.x;
    const int lane = tid & 63;
    const int wv = __builtin_amdgcn_readfirstlane(tid >> 6);
    const int l15 = lane & 15;
    const int quad = lane >> 4;
    if (tid < 128) chs[tid] = 0.f;
    if (tid < 64) {                                /* inline fin1m (bn1 affine) */
        int c = tid;
        double wu[3], wvv[3];
#pragma unroll
        for (int i = 0; i < 3; ++i) {
            wu[i] = (double)W1[c*6 + i];
            wvv[i] = (double)W1[c*6 + 3 + i] - wu[i];
        }
        const double S = (double)SAMPLES;
        double mean = (wu[0]*ms[0] + wu[1]*ms[1] + wu[2]*ms[2]
                     + 20.0*(wvv[0]*ms[3] + wvv[1]*ms[4] + wvv[2]*ms[5])) / S;
        double qM1 = wu[0]*wu[0]*ms[6] + wu[1]*wu[1]*ms[9] + wu[2]*wu[2]*ms[11]
                   + 2.0*(wu[0]*wu[1]*ms[7] + wu[0]*wu[2]*ms[8] + wu[1]*wu[2]*ms[10]);
        double cross = 0.0;
#pragma unroll
        for (int i = 0; i < 3; ++i)
#pragma unroll
            for (int j = 0; j < 3; ++j)
                cross += wu[i] * ms[12 + i*3 + j] * wvv[j];
        double qpp = wvv[0]*wvv[0]*ms[21] + wvv[1]*wvv[1]*ms[24] + wvv[2]*wvv[2]*ms[26]
                   + 2.0*(wvv[0]*wvv[1]*ms[22] + wvv[0]*wvv[2]*ms[23] + wvv[1]*wvv[2]*ms[25]);
        double e2 = (qM1 + 2.0*cross + 20.0*qpp) / S;
        double var = e2 - mean*mean;
        float a = (float)((double)gamma1[c] / sqrt(var + (double)EPSF));
        ab1s[c] = a;
        ab1s[64 + c] = beta1[c] - a * (float)mean;
    }
    __syncthreads();

    bf16x8 whi[8], wlo[8];
#pragma unroll
    for (int t = 0; t < 4; ++t)
#pragma unroll
    for (int f = 0; f < 2; ++f) {
        const int o = 16*t + l15;
        const int c0 = 32*f + quad*8;
        const float4* wr = (const float4*)(W2 + o*64 + c0);
        float4 w0 = wr[0], w1 = wr[1];
        float vals[8] = {w0.x,w0.y,w0.z,w0.w,w1.x,w1.y,w1.z,w1.w};
        bf16x8 h, l;
#pragma unroll
        for (int j = 0; j < 8; ++j) { short hj, lj; bsplit(vals[j], hj, lj); h[j]=hj; l[j]=lj; }
        whi[t*2+f] = h; wlo[t*2+f] = l;
    }

    const float a1 = ab1s[lane], b1 = ab1s[64 + lane];
    float ssum[4] = {0.f,0.f,0.f,0.f}, ssq[4] = {0.f,0.f,0.f,0.f};
    short* thi = &Thi[wv][0];
    short* tlo = &Tlo[wv][0];

    const int pt0 = (blockIdx.x * 4 + wv) * 4;
    const int b = pt0 >> 12;
    const float* ub = u + ((size_t)b << 18);

    for (int p = 0; p < 4; ++p) {
        const int pt = pt0 + p;
        const float vc = v[((size_t)pt << 6) + lane];
        const int* irow = idxb + (size_t)pt * KNN;
#pragma unroll
        for (int k = 0; k < KNN; ++k) {
            int nbr = irow[k];
            float uc = ub[((size_t)nbr << 6) + lane];
            float g = a1 * (uc + vc) + b1;
            g = fmaxf(g, SLOPE * g);
            short hj, lj; bsplit(g, hj, lj);
            thi[k*72 + lane] = hj;
            tlo[k*72 + lane] = lj;
        }
        __builtin_amdgcn_wave_barrier();

        bf16x8 ah1[2], al1[2], ah2[2], al2[2];
#pragma unroll
        for (int f = 0; f < 2; ++f) {
            const int co = 32*f + quad*8;
            ah1[f] = *(const bf16x8*)&thi[l15*72 + co];
            al1[f] = *(const bf16x8*)&tlo[l15*72 + co];
            ah2[f] = *(const bf16x8*)&thi[(16 + l15)*72 + co];
            al2[f] = *(const bf16x8*)&tlo[(16 + l15)*72 + co];
        }

        f32x4 acc1[4], acc2[4];
#pragma unroll
        for (int t = 0; t < 4; ++t) { acc1[t] = (f32x4)0.f; acc2[t] = (f32x4)0.f; }
#pragma unroll
        for (int t = 0; t < 4; ++t) {
#pragma unroll
            for (int f = 0; f < 2; ++f) {
                acc1[t] = __builtin_amdgcn_mfma_f32_16x16x32_bf16(ah1[f], whi[t*2+f], acc1[t], 0,0,0);
                acc1[t] = __builtin_amdgcn_mfma_f32_16x16x32_bf16(al1[f], whi[t*2+f], acc1[t], 0,0,0);
                acc1[t] = __builtin_amdgcn_mfma_f32_16x16x32_bf16(ah1[f], wlo[t*2+f], acc1[t], 0,0,0);
                acc2[t] = __builtin_amdgcn_mfma_f32_16x16x32_bf16(ah2[f], whi[t*2+f], acc2[t], 0,0,0);
                acc2[t] = __builtin_amdgcn_mfma_f32_16x16x32_bf16(al2[f], whi[t*2+f], acc2[t], 0,0,0);
                acc2[t] = __builtin_amdgcn_mfma_f32_16x16x32_bf16(ah2[f], wlo[t*2+f], acc2[t], 0,0,0);
            }
        }
        __builtin_amdgcn_wave_barrier();

        const bool q0 = (quad == 0);
#pragma unroll
        for (int t = 0; t < 4; ++t) {
            float m1 = fmaxf(fmaxf(acc1[t][0], acc1[t][1]), fmaxf(acc1[t][2], acc1[t][3]));
            float s1 = acc1[t][0] + acc1[t][1] + acc1[t][2] + acc1[t][3];
            float q1 = acc1[t][0]*acc1[t][0] + acc1[t][1]*acc1[t][1]
                     + acc1[t][2]*acc1[t][2] + acc1[t][3]*acc1[t][3];
            float m2 = fmaxf(fmaxf(acc2[t][0], acc2[t][1]), fmaxf(acc2[t][2], acc2[t][3]));
            float s2 = acc2[t][0] + acc2[t][1] + acc2[t][2] + acc2[t][3];
            float q2 = acc2[t][0]*acc2[t][0] + acc2[t][1]*acc2[t][1]
                     + acc2[t][2]*acc2[t][2] + acc2[t][3]*acc2[t][3];
            float lm = q0 ? fmaxf(m1, m2) : m1;
            float ls = q0 ? (s1 + s2) : s1;
            float lq = q0 ? (q1 + q2) : q1;
            lm = fmaxf(lm, __shfl_xor(lm, 16)); lm = fmaxf(lm, __shfl_xor(lm, 32));
            ls += __shfl_xor(ls, 16); ls += __shfl_xor(ls, 32);
            lq += __shfl_xor(lq, 16); lq += __shfl_xor(lq, 32);
            if (q0) maxbuf[((size_t)pt << 6) + 16*t + l15] = lm;
            ssum[t] += ls; ssq[t] += lq;
        }
    }

    if (quad == 0) {
#pragma unroll
        for (int t = 0; t < 4; ++t) {
            atomicAdd(&chs[16*t + l15], ssum[t]);
            atomicAdd(&chs[64 + 16*t + l15], ssq[t]);
        }
    }
    __syncthreads();
    if (tid < 128)
        atomicAdd(&stats2f[(blockIdx.x & 1)*128 + tid], chs[tid]);
}

/* ---------------- K7: epilogue — fin2 inlined; transpose + bn2 + lrelu --------- */
__global__ __launch_bounds__(256) void out_kernel(const float* __restrict__ maxbuf,
        const float* __restrict__ s2f, const float* __restrict__ gamma2,
        const float* __restrict__ beta2, float* __restrict__ out) {
    __shared__ float t[64][65];
    __shared__ float ab2s[128];
    const int tid = threadIdx.x;
    if (tid < 64) {                                /* inline fin2 */
        int o = tid;
        double sum = (double)s2f[o] + (double)s2f[128 + o];
        double sq  = (double)s2f[64 + o] + (double)s2f[192 + o];
        double cnt = (double)SAMPLES;
        double mean = sum / cnt;
        double var  = sq / cnt - mean*mean;
        float a = (float)((double)gamma2[o] / sqrt(var + (double)EPSF));
        ab2s[o] = a;
        ab2s[64 + o] = beta2[o] - a * (float)mean;
    }
    const int b = blockIdx.x >> 6;
    const int n0 = (blockIdx.x & 63) << 6;
#pragma unroll
    for (int i = 0; i < 16; ++i) {
        int r = (tid >> 6) + i*4;
        int c = tid & 63;
        t[r][c] = maxbuf[(((size_t)((b << 12) + n0 + r)) << 6) + c];
    }
    __syncthreads();
#pragma unroll
    for (int i = 0; i < 16; ++i) {
        int o = (tid >> 6) + i*4;
        int nn = tid & 63;
        float a = ab2s[o], bb = ab2s[64 + o];
        float h = a * t[nn][o] + bb;
        out[(((size_t)(b*64 + o)) << 12) + n0 + nn] = h >= 0.f ? h : SLOPE*h;
    }
}

extern "C" void kernel_launch(void* const* d_in, const int* in_sizes, int n_in,
                              void* d_out, int out_size, void* d_ws, size_t ws_size,
                              hipStream_t stream) {
    const float* x      = (const float*)d_in[0];
    const float* W1     = (const float*)d_in[1];
    const float* gamma1 = (const float*)d_in[2];
    const float* beta1  = (const float*)d_in[3];
    const float* W2     = (const float*)d_in[4];
    const float* gamma2 = (const float*)d_in[5];
    const float* beta2  = (const float*)d_in[6];
    float* out = (float*)d_out;

    char* ws = (char*)d_ws;
    int*    idxb    = (int*)   (ws + 0);           /* 2,621,440 B */
    float*  u       = (float*) (ws + 2621440);     /* 8,388,608 B */
    float*  v       = (float*) (ws + 11010048);    /* 8,388,608 B */
    float*  maxbuf  = (float*) (ws + 19398656);    /* 8,388,608 B, (b,n,o) */
    float4* pts4    = (float4*)(ws + 19398656);    /* 512 KB alias (dead pre-main) */
    double* mstats  = (double*)(ws + 27787264);    /* 27 doubles */
    float*  stats2f = (float*) (ws + 27787520);    /* 2x128 floats */
    float2* zbuf    = (float2*)(ws + 27787264);    /* zero region = mstats+stats2f */

    pts4_kernel   <<<128, 256, 0, stream>>>(x, pts4, zbuf);
    knn_kernel    <<<8192, 256, 0, stream>>>(pts4, idxb);
    uv_kernel     <<<8192, 256, 0, stream>>>(x, W1, u, v);
    moments_kernel<<<128, 256, 0, stream>>>(pts4, idxb, mstats);
    main_kernel   <<<2048, 256, 0, stream>>>(idxb, u, v, mstats, W1, gamma1, beta1,
                                             W2, maxbuf, stats2f);
    out_kernel    <<<512, 256, 0, stream>>>(maxbuf, stats2f, gamma2, beta2, out);
}

// Round 10
// 345.383 us; speedup vs baseline: 1.2623x; 1.0015x over previous
//
#include <hip/hip_runtime.h>
#include <hip/hip_bf16.h>
#include <math.h>

#define BB 8
#define NN 4096
#define KNN 20
#define CH 64
#define SAMPLES (BB*NN*KNN)   /* 655360 */
#define EPSF 1e-5f
#define SLOPE 0.2f
#define QPW 4                 /* queries per wave in knn */

typedef float f32x4 __attribute__((ext_vector_type(4)));
typedef short bf16x8 __attribute__((ext_vector_type(8)));

/* decode order-preserving uint back to float */
__device__ __forceinline__ float key_decode(unsigned e) {
    return __uint_as_float((e & 0x80000000u) ? (e ^ 0x80000000u) : ~e);
}

/* rank-select flush: merge ovf[0..cnt) + inc[0..19] -> new exact top-20 in inc. */
__device__ __forceinline__ void rank_flush(unsigned long long* ovf,
                                           unsigned long long* inc,
                                           unsigned long long* scr,
                                           int& cnt, float& kthd, int lane) {
    while (cnt > 0) {
        int take = cnt < 44 ? cnt : 44;
        unsigned long long key;
        if (lane < take)      key = ovf[cnt - take + lane];
        else if (lane >= 44)  key = inc[lane - 44];
        else                  key = ~0ull;
        scr[lane] = key;
        __builtin_amdgcn_wave_barrier();
        int r = 0;
#pragma unroll
        for (int t = 0; t < 64; ++t) {
            unsigned long long kt = scr[t];       /* uniform addr -> broadcast */
            r += (kt < key) ? 1 : 0;
        }
        __builtin_amdgcn_wave_barrier();
        if (r < KNN) inc[r] = key;                /* padding ranks land >= 20 */
        __builtin_amdgcn_wave_barrier();
        kthd = key_decode((unsigned)(inc[KNN-1] >> 32));
        cnt -= take;
    }
}

/* ---------------- K0: pts in screen format (-2x,-2y,-2z,sq); zero stats ------- */
__global__ void pts4_kernel(const float* __restrict__ x, float4* __restrict__ pts4,
                            float2* __restrict__ zbuf) {
#pragma clang fp contract(off)
    int t = blockIdx.x * 256 + threadIdx.x;       /* 32768 points */
    if (blockIdx.x == 0 && threadIdx.x < 160)     /* zero mstats+stats2f */
        zbuf[threadIdx.x] = make_float2(0.f, 0.f);
    int b = t >> 12;
    int n = t & (NN - 1);
    const float* xb = x + (size_t)b * 3 * NN;
    float mx = xb[n], my = xb[NN + n], mz = xb[2*NN + n];
    float sq = mx*mx; sq += my*my; sq += mz*mz;   /* ref summation order */
    pts4[t] = make_float4(-2.0f*mx, -2.0f*my, -2.0f*mz, sq);  /* exact scalings */
}

/* ---------------- K1: exact KNN. 4 queries/wave; screen + exact keys ----------- */
__global__ __launch_bounds__(256) void knn_kernel(const float4* __restrict__ pts4,
                                                  int* __restrict__ idx_out) {
#pragma clang fp contract(off)
    __shared__ unsigned long long OVF[4][QPW][96];   /* 12 KB  */
    __shared__ unsigned long long INC[4][QPW][20];   /* 2.5 KB */
    __shared__ unsigned long long SCR[4][64];        /* 2 KB   */
    const int tid = threadIdx.x;
    const int lane = tid & 63;
    const int wv = __builtin_amdgcn_readfirstlane(tid >> 6);
    const int qb = (blockIdx.x * 4 + wv) * QPW;      /* 4 consecutive queries */
    const int b = qb >> 12;
    const int n0 = qb & (NN - 1);
    const float4* base = pts4 + ((size_t)b << 12);
    unsigned long long* scr = &SCR[wv][0];

    float qx[QPW], qy[QPW], qz[QPW], sqn[QPW], kthd[QPW], thr[QPW];
    int cnt[QPW];
#pragma unroll
    for (int i = 0; i < QPW; ++i) {
        float4 Qc = base[n0 + i];
        qx[i] = -0.5f*Qc.x; qy[i] = -0.5f*Qc.y; qz[i] = -0.5f*Qc.z;  /* exact */
        sqn[i] = Qc.w;
        cnt[i] = 0;
    }

    /* j == 0 batch: exact d for first 64 candidates, rank-select per query */
    {
        const float4 P = base[lane];
        const float mx = -0.5f*P.x, my = -0.5f*P.y, mz = -0.5f*P.z;
#pragma unroll
        for (int i = 0; i < QPW; ++i) {
            float inner = qx[i]*mx; inner += qy[i]*my; inner += qz[i]*mz;
            const float d = (sqn[i] - 2.0f*inner) + P.w;     /* ref parenthesization */
            unsigned uu = __float_as_uint(d);
            unsigned e = uu ^ (((unsigned)((int)uu >> 31)) | 0x80000000u);
            unsigned long long key = ((unsigned long long)e << 32) | (unsigned)lane;
            scr[lane] = key;
            __builtin_amdgcn_wave_barrier();
            int r = 0;
#pragma unroll
            for (int t = 0; t < 64; ++t) {
                unsigned long long kt = scr[t];
                r += (kt < key) ? 1 : 0;
            }
            __builtin_amdgcn_wave_barrier();
            if (r < KNN) INC[wv][i][r] = key;
            __builtin_amdgcn_wave_barrier();
            kthd[i] = key_decode((unsigned)(INC[wv][i][KNN-1] >> 32));
            thr[i] = (kthd[i] - sqn[i]) + 1e-3f*(fabsf(kthd[i]) + fabsf(sqn[i]) + 1.0f);
        }
    }

    float4 Pn = base[64 + lane];
    for (int j = 1; j < 64; ++j) {
        const float4 P = Pn;
        if (j < 63) Pn = base[((j + 1) << 6) + lane];
        const int m = (j << 6) | lane;
#pragma unroll
        for (int i = 0; i < QPW; ++i) {
            if (cnt[i] > 32) {                     /* wave-uniform */
                rank_flush(&OVF[wv][i][0], &INC[wv][i][0], scr, cnt[i], kthd[i], lane);
                thr[i] = (kthd[i] - sqn[i]) + 1e-3f*(fabsf(kthd[i]) + fabsf(sqn[i]) + 1.0f);
            }
            /* screen: s ~= d - sqn (3 fma). Conservative: over-push only. */
            const float s = fmaf(P.x, qx[i], fmaf(P.y, qy[i], fmaf(P.z, qz[i], P.w)));
            bool push = s <= thr[i];
            unsigned long long mask = __ballot(push);
            if (mask) {
                if (push) {                        /* rare: exact bitwise key */
                    const float mx = -0.5f*P.x, my = -0.5f*P.y, mz = -0.5f*P.z;
                    float inner = qx[i]*mx; inner += qy[i]*my; inner += qz[i]*mz;
                    const float d = (sqn[i] - 2.0f*inner) + P.w;
                    unsigned uu = __float_as_uint(d);
                    unsigned e = uu ^ (((unsigned)((int)uu >> 31)) | 0x80000000u);
                    unsigned long long key = ((unsigned long long)e << 32) | (unsigned)m;
                    int ofs = (int)__popcll(mask & ((1ull << lane) - 1ull));
                    OVF[wv][i][cnt[i] + ofs] = key;
                }
                cnt[i] += (int)__popcll(mask);
            }
        }
    }
#pragma unroll
    for (int i = 0; i < QPW; ++i) {
        rank_flush(&OVF[wv][i][0], &INC[wv][i][0], scr, cnt[i], kthd[i], lane);
        if (lane < KNN)
            idx_out[(size_t)(qb + i) * KNN + lane] =
                (int)(unsigned)(INC[wv][i][lane] & 0xFFFFFFFFull);
    }
}

/* ---------------- K3: bn1 via point moments (coords recovered exactly) --------- */
__global__ __launch_bounds__(128) void moments_kernel(const float4* __restrict__ pts4,
        const int* __restrict__ idxb, double* __restrict__ mstats) {
    const int t = blockIdx.x * 128 + threadIdx.x;
    const int b = t >> 12;
    const float4* base = pts4 + ((size_t)b << 12);
    const float4 pc = base[t & (NN - 1)];
    const float px = -0.5f*pc.x, py = -0.5f*pc.y, pz = -0.5f*pc.z;
    const int* irow = idxb + (size_t)t * KNN;
    float sx = 0.f, sy = 0.f, sz = 0.f;
    float m1[6] = {0.f,0.f,0.f,0.f,0.f,0.f};
    for (int k = 0; k < KNN; ++k) {
        float4 pn = base[irow[k]];
        float nx = -0.5f*pn.x, ny = -0.5f*pn.y, nz = -0.5f*pn.z;
        sx += nx; sy += ny; sz += nz;
        m1[0] = fmaf(nx, nx, m1[0]); m1[1] = fmaf(nx, ny, m1[1]);
        m1[2] = fmaf(nx, nz, m1[2]); m1[3] = fmaf(ny, ny, m1[3]);
        m1[4] = fmaf(ny, nz, m1[4]); m1[5] = fmaf(nz, nz, m1[5]);
    }
    float mom[27] = {
        sx, sy, sz,  px, py, pz,
        m1[0], m1[1], m1[2], m1[3], m1[4], m1[5],
        sx*px, sx*py, sx*pz,  sy*px, sy*py, sy*pz,  sz*px, sz*py, sz*pz,
        px*px, px*py, px*pz, py*py, py*pz, pz*pz };
#pragma unroll
    for (int i = 0; i < 27; ++i) {
        float vsum = mom[i];
#pragma unroll
        for (int off = 32; off > 0; off >>= 1) vsum += __shfl_xor(vsum, off);
        if ((threadIdx.x & 63) == 0) atomicAdd(&mstats[i], (double)vsum);
    }
}

/* split fp32 -> bf16 hi (truncate) + bf16 lo (truncated remainder) */
__device__ __forceinline__ void bsplit(float g, short& hi, short& lo) {
    unsigned bits = __float_as_uint(g);
    unsigned hbits = bits & 0xFFFF0000u;
    float rem = g - __uint_as_float(hbits);
    hi = (short)(bits >> 16);
    lo = (short)(__float_as_uint(rem) >> 16);
}

/* ---------------- K5: main pass — u,v inline from pts4; split-bf16 MFMA -------- */
__global__ __launch_bounds__(256) void main_kernel(const int* __restrict__ idxb,
        const float4* __restrict__ pts4,
        const double* __restrict__ ms, const float* __restrict__ W1,
        const float* __restrict__ gamma1, const float* __restrict__ beta1,
        const float* __restrict__ W2,
        float* __restrict__ maxbuf, float* __restrict__ stats2f) {
    __shared__ __align__(16) short Thi[4][32*72];
    __shared__ __align__(16) short Tlo[4][32*72];
    __shared__ float chs[128];
    __shared__ float ab1s[128];
    const int tid = threadIdx.x;
    const int lane = tid & 63;
    const int wv = __builtin_amdgcn_readfirstlane(tid >> 6);
    const int l15 = lane & 15;
    const int quad = lane >> 4;
    if (tid < 128) chs[tid] = 0.f;
    if (tid < 64) {                                /* inline fin1m (bn1 affine) */
        int c = tid;
        double wu[3], wvv[3];
#pragma unroll
        for (int i = 0; i < 3; ++i) {
            wu[i] = (double)W1[c*6 + i];
            wvv[i] = (double)W1[c*6 + 3 + i] - wu[i];
        }
        const double S = (double)SAMPLES;
        double mean = (wu[0]*ms[0] + wu[1]*ms[1] + wu[2]*ms[2]
                     + 20.0*(wvv[0]*ms[3] + wvv[1]*ms[4] + wvv[2]*ms[5])) / S;
        double qM1 = wu[0]*wu[0]*ms[6] + wu[1]*wu[1]*ms[9] + wu[2]*wu[2]*ms[11]
                   + 2.0*(wu[0]*wu[1]*ms[7] + wu[0]*wu[2]*ms[8] + wu[1]*wu[2]*ms[10]);
        double cross = 0.0;
#pragma unroll
        for (int i = 0; i < 3; ++i)
#pragma unroll
            for (int j = 0; j < 3; ++j)
                cross += wu[i] * ms[12 + i*3 + j] * wvv[j];
        double qpp = wvv[0]*wvv[0]*ms[21] + wvv[1]*wvv[1]*ms[24] + wvv[2]*wvv[2]*ms[26]
                   + 2.0*(wvv[0]*wvv[1]*ms[22] + wvv[0]*wvv[2]*ms[23] + wvv[1]*wvv[2]*ms[25]);
        double e2 = (qM1 + 2.0*cross + 20.0*qpp) / S;
        double var = e2 - mean*mean;
        float a = (float)((double)gamma1[c] / sqrt(var + (double)EPSF));
        ab1s[c] = a;
        ab1s[64 + c] = beta1[c] - a * (float)mean;
    }
    __syncthreads();

    bf16x8 whi[8], wlo[8];
#pragma unroll
    for (int t = 0; t < 4; ++t)
#pragma unroll
    for (int f = 0; f < 2; ++f) {
        const int o = 16*t + l15;
        const int c0 = 32*f + quad*8;
        const float4* wr = (const float4*)(W2 + o*64 + c0);
        float4 w0 = wr[0], w1 = wr[1];
        float vals[8] = {w0.x,w0.y,w0.z,w0.w,w1.x,w1.y,w1.z,w1.w};
        bf16x8 h, l;
#pragma unroll
        for (int j = 0; j < 8; ++j) { short hj, lj; bsplit(vals[j], hj, lj); h[j]=hj; l[j]=lj; }
        whi[t*2+f] = h; wlo[t*2+f] = l;
    }

    /* per-lane W1 row (lane = channel) */
    const float w10 = W1[lane*6+0], w11 = W1[lane*6+1], w12 = W1[lane*6+2];
    const float w13 = W1[lane*6+3], w14 = W1[lane*6+4], w15 = W1[lane*6+5];
    const float a1 = ab1s[lane], b1 = ab1s[64 + lane];
    float ssum[4] = {0.f,0.f,0.f,0.f}, ssq[4] = {0.f,0.f,0.f,0.f};
    short* thi = &Thi[wv][0];
    short* tlo = &Tlo[wv][0];

    const int pt0 = (blockIdx.x * 4 + wv) * 4;
    const int b = pt0 >> 12;
    const float4* pb = pts4 + ((size_t)b << 12);

    for (int p = 0; p < 4; ++p) {
        const int pt = pt0 + p;
        const float4 pc = pb[pt & (NN - 1)];
        const float X = -0.5f*pc.x, Y = -0.5f*pc.y, Z = -0.5f*pc.z;  /* exact */
        const float vc = (w13 - w10)*X + (w14 - w11)*Y + (w15 - w12)*Z;
        const int* irow = idxb + (size_t)pt * KNN;  /* uniform -> s_load */
#pragma unroll
        for (int k = 0; k < KNN; ++k) {
            float4 pn = pb[irow[k]];                /* uniform 16B broadcast load */
            float nx = -0.5f*pn.x, ny = -0.5f*pn.y, nz = -0.5f*pn.z;
            float uc = w10*nx + w11*ny + w12*nz;
            float g = a1 * (uc + vc) + b1;
            g = fmaxf(g, SLOPE * g);
            short hj, lj; bsplit(g, hj, lj);
            thi[k*72 + lane] = hj;
            tlo[k*72 + lane] = lj;
        }
        __builtin_amdgcn_wave_barrier();

        bf16x8 ah1[2], al1[2], ah2[2], al2[2];
#pragma unroll
        for (int f = 0; f < 2; ++f) {
            const int co = 32*f + quad*8;
            ah1[f] = *(const bf16x8*)&thi[l15*72 + co];
            al1[f] = *(const bf16x8*)&tlo[l15*72 + co];
            ah2[f] = *(const bf16x8*)&thi[(16 + l15)*72 + co];
            al2[f] = *(const bf16x8*)&tlo[(16 + l15)*72 + co];
        }

        f32x4 acc1[4], acc2[4];
#pragma unroll
        for (int t = 0; t < 4; ++t) { acc1[t] = (f32x4)0.f; acc2[t] = (f32x4)0.f; }
#pragma unroll
        for (int t = 0; t < 4; ++t) {
#pragma unroll
            for (int f = 0; f < 2; ++f) {
                acc1[t] = __builtin_amdgcn_mfma_f32_16x16x32_bf16(ah1[f], whi[t*2+f], acc1[t], 0,0,0);
                acc1[t] = __builtin_amdgcn_mfma_f32_16x16x32_bf16(al1[f], whi[t*2+f], acc1[t], 0,0,0);
                acc1[t] = __builtin_amdgcn_mfma_f32_16x16x32_bf16(ah1[f], wlo[t*2+f], acc1[t], 0,0,0);
                acc2[t] = __builtin_amdgcn_mfma_f32_16x16x32_bf16(ah2[f], whi[t*2+f], acc2[t], 0,0,0);
                acc2[t] = __builtin_amdgcn_mfma_f32_16x16x32_bf16(al2[f], whi[t*2+f], acc2[t], 0,0,0);
                acc2[t] = __builtin_amdgcn_mfma_f32_16x16x32_bf16(ah2[f], wlo[t*2+f], acc2[t], 0,0,0);
            }
        }
        __builtin_amdgcn_wave_barrier();

        const bool q0 = (quad == 0);
#pragma unroll
        for (int t = 0; t < 4; ++t) {
            float m1 = fmaxf(fmaxf(acc1[t][0], acc1[t][1]), fmaxf(acc1[t][2], acc1[t][3]));
            float s1 = acc1[t][0] + acc1[t][1] + acc1[t][2] + acc1[t][3];
            float q1 = acc1[t][0]*acc1[t][0] + acc1[t][1]*acc1[t][1]
                     + acc1[t][2]*acc1[t][2] + acc1[t][3]*acc1[t][3];
            float m2 = fmaxf(fmaxf(acc2[t][0], acc2[t][1]), fmaxf(acc2[t][2], acc2[t][3]));
            float s2 = acc2[t][0] + acc2[t][1] + acc2[t][2] + acc2[t][3];
            float q2 = acc2[t][0]*acc2[t][0] + acc2[t][1]*acc2[t][1]
                     + acc2[t][2]*acc2[t][2] + acc2[t][3]*acc2[t][3];
            float lm = q0 ? fmaxf(m1, m2) : m1;
            float ls = q0 ? (s1 + s2) : s1;
            float lq = q0 ? (q1 + q2) : q1;
            lm = fmaxf(lm, __shfl_xor(lm, 16)); lm = fmaxf(lm, __shfl_xor(lm, 32));
            ls += __shfl_xor(ls, 16); ls += __shfl_xor(ls, 32);
            lq += __shfl_xor(lq, 16); lq += __shfl_xor(lq, 32);
            if (q0) maxbuf[((size_t)pt << 6) + 16*t + l15] = lm;
            ssum[t] += ls; ssq[t] += lq;
        }
    }

    if (quad == 0) {
#pragma unroll
        for (int t = 0; t < 4; ++t) {
            atomicAdd(&chs[16*t + l15], ssum[t]);
            atomicAdd(&chs[64 + 16*t + l15], ssq[t]);
        }
    }
    __syncthreads();
    if (tid < 128)
        atomicAdd(&stats2f[(blockIdx.x & 1)*128 + tid], chs[tid]);
}

/* ---------------- K7: epilogue — fin2 inlined; transpose + bn2 + lrelu --------- */
__global__ __launch_bounds__(256) void out_kernel(const float* __restrict__ maxbuf,
        const float* __restrict__ s2f, const float* __restrict__ gamma2,
        const float* __restrict__ beta2, float* __restrict__ out) {
    __shared__ float t[64][65];
    __shared__ float ab2s[128];
    const int tid = threadIdx.x;
    if (tid < 64) {                                /* inline fin2 */
        int o = tid;
        double sum = (double)s2f[o] + (double)s2f[128 + o];
        double sq  = (double)s2f[64 + o] + (double)s2f[192 + o];
        double cnt = (double)SAMPLES;
        double mean = sum / cnt;
        double var  = sq / cnt - mean*mean;
        float a = (float)((double)gamma2[o] / sqrt(var + (double)EPSF));
        ab2s[o] = a;
        ab2s[64 + o] = beta2[o] - a * (float)mean;
    }
    const int b = blockIdx.x >> 6;
    const int n0 = (blockIdx.x & 63) << 6;
#pragma unroll
    for (int i = 0; i < 16; ++i) {
        int r = (tid >> 6) + i*4;
        int c = tid & 63;
        t[r][c] = maxbuf[(((size_t)((b << 12) + n0 + r)) << 6) + c];
    }
    __syncthreads();
#pragma unroll
    for (int i = 0; i < 16; ++i) {
        int o = (tid >> 6) + i*4;
        int nn = tid & 63;
        float a = ab2s[o], bb = ab2s[64 + o];
        float h = a * t[nn][o] + bb;
        out[(((size_t)(b*64 + o)) << 12) + n0 + nn] = h >= 0.f ? h : SLOPE*h;
    }
}

extern "C" void kernel_launch(void* const* d_in, const int* in_sizes, int n_in,
                              void* d_out, int out_size, void* d_ws, size_t ws_size,
                              hipStream_t stream) {
    const float* x      = (const float*)d_in[0];
    const float* W1     = (const float*)d_in[1];
    const float* gamma1 = (const float*)d_in[2];
    const float* beta1  = (const float*)d_in[3];
    const float* W2     = (const float*)d_in[4];
    const float* gamma2 = (const float*)d_in[5];
    const float* beta2  = (const float*)d_in[6];
    float* out = (float*)d_out;

    char* ws = (char*)d_ws;
    int*    idxb    = (int*)   (ws + 0);           /* 2,621,440 B */
    float4* pts4    = (float4*)(ws + 2621440);     /* 512 KB (u/v region freed) */
    float*  maxbuf  = (float*) (ws + 19398656);    /* 8,388,608 B, (b,n,o) */
    double* mstats  = (double*)(ws + 27787264);    /* 27 doubles */
    float*  stats2f = (float*) (ws + 27787520);    /* 2x128 floats */
    float2* zbuf    = (float2*)(ws + 27787264);    /* zero region = mstats+stats2f */

    pts4_kernel   <<<128, 256, 0, stream>>>(x, pts4, zbuf);
    knn_kernel    <<<2048, 256, 0, stream>>>(pts4, idxb);
    moments_kernel<<<256, 128, 0, stream>>>(pts4, idxb, mstats);
    main_kernel   <<<2048, 256, 0, stream>>>(idxb, pts4, mstats, W1, gamma1, beta1,
                                             W2, maxbuf, stats2f);
    out_kernel    <<<512, 256, 0, stream>>>(maxbuf, stats2f, gamma2, beta2, out);
}

// Round 11
// 269.030 us; speedup vs baseline: 1.6205x; 1.2838x over previous
//
#include <hip/hip_runtime.h>
#include <hip/hip_bf16.h>
#include <math.h>

#define BB 8
#define NN 4096
#define KNN 20
#define CH 64
#define SAMPLES (BB*NN*KNN)   /* 655360 */
#define EPSF 1e-5f
#define SLOPE 0.2f

typedef float f32x4 __attribute__((ext_vector_type(4)));
typedef short bf16x8 __attribute__((ext_vector_type(8)));

/* decode order-preserving uint back to float */
__device__ __forceinline__ float key_decode(unsigned e) {
    return __uint_as_float((e & 0x80000000u) ? (e ^ 0x80000000u) : ~e);
}

/* rank-select flush: merge ovf[0..cnt) + inc[0..19] -> new exact top-20 in inc. */
__device__ __forceinline__ void rank_flush(unsigned long long* ovf,
                                           unsigned long long* inc,
                                           unsigned long long* scr,
                                           int& cnt, float& kthd, int lane) {
    while (cnt > 0) {
        int take = cnt < 44 ? cnt : 44;
        unsigned long long key;
        if (lane < take)      key = ovf[cnt - take + lane];
        else if (lane >= 44)  key = inc[lane - 44];
        else                  key = ~0ull;
        scr[lane] = key;
        __builtin_amdgcn_wave_barrier();
        int r = 0;
#pragma unroll
        for (int t = 0; t < 64; ++t) {
            unsigned long long kt = scr[t];       /* uniform addr -> broadcast */
            r += (kt < key) ? 1 : 0;
        }
        __builtin_amdgcn_wave_barrier();
        if (r < KNN) inc[r] = key;                /* padding ranks land >= 20 */
        __builtin_amdgcn_wave_barrier();
        kthd = key_decode((unsigned)(inc[KNN-1] >> 32));
        cnt -= take;
    }
}

/* ---------------- K0: pts in screen format (-2x,-2y,-2z,sq); zero stats ------- */
__global__ void pts4_kernel(const float* __restrict__ x, float4* __restrict__ pts4,
                            float2* __restrict__ zbuf) {
#pragma clang fp contract(off)
    int t = blockIdx.x * 256 + threadIdx.x;       /* 32768 points */
    if (blockIdx.x == 0 && threadIdx.x < 160)     /* zero mstats+stats2f */
        zbuf[threadIdx.x] = make_float2(0.f, 0.f);
    int b = t >> 12;
    int n = t & (NN - 1);
    const float* xb = x + (size_t)b * 3 * NN;
    float mx = xb[n], my = xb[NN + n], mz = xb[2*NN + n];
    float sq = mx*mx; sq += my*my; sq += mz*mz;   /* ref summation order */
    pts4[t] = make_float4(-2.0f*mx, -2.0f*my, -2.0f*mz, sq);  /* exact scalings */
}

/* ---------------- K0b: per-batch bitonic sort by x (key=ope(x)|idx) ------------ */
__global__ __launch_bounds__(1024) void sort_kernel(const float4* __restrict__ pts4,
        float4* __restrict__ sp4, int* __restrict__ sidx, int* __restrict__ rankArr) {
#pragma clang fp contract(off)
    __shared__ unsigned long long S[NN];                     /* 32 KB */
    const int tid = threadIdx.x;
    const int b = blockIdx.x;
    const float4* base = pts4 + ((size_t)b << 12);
    for (int i = tid; i < NN; i += 1024) {
        float xq = -0.5f * base[i].x;             /* exact original x */
        unsigned uu = __float_as_uint(xq);
        unsigned e = uu ^ (((unsigned)((int)uu >> 31)) | 0x80000000u);
        S[i] = ((unsigned long long)e << 32) | (unsigned)i;
    }
    __syncthreads();
    for (int k = 2; k <= NN; k <<= 1) {
        for (int j = k >> 1; j > 0; j >>= 1) {
#pragma unroll
            for (int tt = 0; tt < 2; ++tt) {
                int t = tid + tt*1024;            /* 2048 pairs */
                int i = ((t & ~(j - 1)) << 1) | (t & (j - 1));
                int h = i | j;
                unsigned long long a = S[i], c = S[h];
                bool up = ((i & k) == 0);
                if ((a > c) == up) { S[i] = c; S[h] = a; }
            }
            __syncthreads();
        }
    }
    for (int s = tid; s < NN; s += 1024) {
        int oi = (int)(unsigned)(S[s] & 0xFFFFFFFFu);
        sp4[(b << 12) + s] = base[oi];
        sidx[(b << 12) + s] = oi;
        rankArr[(b << 12) + oi] = s;
    }
}

/* ---------------- K1: exact KNN — sorted sweep with provable pruning ----------- */
__global__ __launch_bounds__(256) void knn_kernel(const float4* __restrict__ pts4,
        const float4* __restrict__ sp4, const int* __restrict__ sidx,
        const int* __restrict__ rankArr, int* __restrict__ idx_out) {
#pragma clang fp contract(off)
    __shared__ unsigned long long OVF[4][96];                /* 3 KB   */
    __shared__ unsigned long long INC[4][24];
    __shared__ unsigned long long SCR[4][64];
    const int tid = threadIdx.x;
    const int lane = tid & 63;
    const int wv = __builtin_amdgcn_readfirstlane(tid >> 6);
    const int q = blockIdx.x * 4 + wv;                       /* one query/wave */
    const int b = q >> 12;
    const float4* sb = sp4 + ((size_t)b << 12);
    const int* si = sidx + ((size_t)b << 12);
    unsigned long long* ovf = &OVF[wv][0];
    unsigned long long* inc = &INC[wv][0];
    unsigned long long* scr = &SCR[wv][0];

    const float4 Qc = pts4[q];
    const float qx = -0.5f*Qc.x, qy = -0.5f*Qc.y, qz = -0.5f*Qc.z; /* exact coords */
    const float sqn = Qc.w;
    const int pos = rankArr[q];
    int c0 = pos - 32; c0 = c0 < 0 ? 0 : (c0 > NN-64 ? NN-64 : c0);
    float kthd, thr, M;
    int cnt = 0;

    /* prefill: exact d for the 64 nearest-in-x, rank-select directly */
    {
        const float4 P = sb[c0 + lane];
        const float mx = -0.5f*P.x, my = -0.5f*P.y, mz = -0.5f*P.z;
        float inner = qx*mx; inner += qy*my; inner += qz*mz;
        const float d = (sqn - 2.0f*inner) + P.w;            /* ref parenthesization */
        unsigned uu = __float_as_uint(d);
        unsigned e = uu ^ (((unsigned)((int)uu >> 31)) | 0x80000000u);
        unsigned long long key = ((unsigned long long)e << 32) | (unsigned)si[c0 + lane];
        scr[lane] = key;
        __builtin_amdgcn_wave_barrier();
        int r = 0;
#pragma unroll
        for (int t = 0; t < 64; ++t) {
            unsigned long long kt = scr[t];
            r += (kt < key) ? 1 : 0;
        }
        __builtin_amdgcn_wave_barrier();
        if (r < KNN) inc[r] = key;
        __builtin_amdgcn_wave_barrier();
        kthd = key_decode((unsigned)(inc[KNN-1] >> 32));
        M = 1e-3f*(fabsf(kthd) + fabsf(sqn) + 1.0f);
        thr = (kthd - sqn) + M;
    }

    int lo = c0, hi = c0 + 64;
    bool dl = (lo == 0), dr = (hi == NN);

    while (!dl || !dr) {
        if (!dl) {
            const float xb = -0.5f*sb[lo-1].x;               /* nearest unprocessed */
            const float dx = qx - xb;
            if (dx*dx > kthd + M) dl = true;                 /* provably all farther */
            else {
                if (cnt > 32) {
                    rank_flush(ovf, inc, scr, cnt, kthd, lane);
                    M = 1e-3f*(fabsf(kthd) + fabsf(sqn) + 1.0f);
                    thr = (kthd - sqn) + M;
                }
                int st = lo - 64; if (st < 0) st = 0;
                const int s = st + lane;
                const bool valid = s < lo;
                const float4 P = sb[s];                      /* s < lo <= NN, in-range */
                const float sc = fmaf(P.x, qx, fmaf(P.y, qy, fmaf(P.z, qz, P.w)));
                bool push = valid && (sc <= thr);
                unsigned long long mask = __ballot(push);
                if (mask) {
                    if (push) {
                        const float mx = -0.5f*P.x, my = -0.5f*P.y, mz = -0.5f*P.z;
                        float inner = qx*mx; inner += qy*my; inner += qz*mz;
                        const float d = (sqn - 2.0f*inner) + P.w;
                        unsigned uu = __float_as_uint(d);
                        unsigned e = uu ^ (((unsigned)((int)uu >> 31)) | 0x80000000u);
                        unsigned long long key = ((unsigned long long)e << 32) | (unsigned)si[s];
                        int ofs = (int)__popcll(mask & ((1ull << lane) - 1ull));
                        ovf[cnt + ofs] = key;
                    }
                    cnt += (int)__popcll(mask);
                }
                lo = st;
                dl = (lo == 0);
            }
        }
        if (!dr) {
            const float xb = -0.5f*sb[hi].x;
            const float dx = xb - qx;
            if (dx*dx > kthd + M) dr = true;
            else {
                if (cnt > 32) {
                    rank_flush(ovf, inc, scr, cnt, kthd, lane);
                    M = 1e-3f*(fabsf(kthd) + fabsf(sqn) + 1.0f);
                    thr = (kthd - sqn) + M;
                }
                int en = hi + 64; if (en > NN) en = NN;
                const int s = hi + lane;
                const int sa = s < NN-1 ? s : NN-1;          /* clamp OOB lanes */
                const bool valid = s < en;
                const float4 P = sb[sa];
                const float sc = fmaf(P.x, qx, fmaf(P.y, qy, fmaf(P.z, qz, P.w)));
                bool push = valid && (sc <= thr);
                unsigned long long mask = __ballot(push);
                if (mask) {
                    if (push) {
                        const float mx = -0.5f*P.x, my = -0.5f*P.y, mz = -0.5f*P.z;
                        float inner = qx*mx; inner += qy*my; inner += qz*mz;
                        const float d = (sqn - 2.0f*inner) + P.w;
                        unsigned uu = __float_as_uint(d);
                        unsigned e = uu ^ (((unsigned)((int)uu >> 31)) | 0x80000000u);
                        unsigned long long key = ((unsigned long long)e << 32) | (unsigned)si[sa];
                        int ofs = (int)__popcll(mask & ((1ull << lane) - 1ull));
                        ovf[cnt + ofs] = key;
                    }
                    cnt += (int)__popcll(mask);
                }
                hi = en;
                dr = (hi == NN);
            }
        }
    }
    rank_flush(ovf, inc, scr, cnt, kthd, lane);
    if (lane < KNN)
        idx_out[(size_t)q * KNN + lane] = (int)(unsigned)(inc[lane] & 0xFFFFFFFFull);
}

/* ---------------- K3: bn1 via point moments; block-reduced atomics ------------- */
__global__ __launch_bounds__(256) void moments_kernel(const float4* __restrict__ pts4,
        const int* __restrict__ idxb, double* __restrict__ mstats) {
    __shared__ float red[4][27];
    const int t = blockIdx.x * 256 + threadIdx.x;
    const int lane = threadIdx.x & 63;
    const int wv = __builtin_amdgcn_readfirstlane(threadIdx.x >> 6);
    const int b = t >> 12;
    const float4* base = pts4 + ((size_t)b << 12);
    const float4 pc = base[t & (NN - 1)];
    const float px = -0.5f*pc.x, py = -0.5f*pc.y, pz = -0.5f*pc.z;
    const int* irow = idxb + (size_t)t * KNN;
    float sx = 0.f, sy = 0.f, sz = 0.f;
    float m1[6] = {0.f,0.f,0.f,0.f,0.f,0.f};
    for (int k = 0; k < KNN; ++k) {
        float4 pn = base[irow[k]];
        float nx = -0.5f*pn.x, ny = -0.5f*pn.y, nz = -0.5f*pn.z;
        sx += nx; sy += ny; sz += nz;
        m1[0] = fmaf(nx, nx, m1[0]); m1[1] = fmaf(nx, ny, m1[1]);
        m1[2] = fmaf(nx, nz, m1[2]); m1[3] = fmaf(ny, ny, m1[3]);
        m1[4] = fmaf(ny, nz, m1[4]); m1[5] = fmaf(nz, nz, m1[5]);
    }
    float mom[27] = {
        sx, sy, sz,  px, py, pz,
        m1[0], m1[1], m1[2], m1[3], m1[4], m1[5],
        sx*px, sx*py, sx*pz,  sy*px, sy*py, sy*pz,  sz*px, sz*py, sz*pz,
        px*px, px*py, px*pz, py*py, py*pz, pz*pz };
#pragma unroll
    for (int i = 0; i < 27; ++i) {
        float vsum = mom[i];
#pragma unroll
        for (int off = 32; off > 0; off >>= 1) vsum += __shfl_xor(vsum, off);
        if (lane == 0) red[wv][i] = vsum;
    }
    __syncthreads();
    if (threadIdx.x < 27)
        atomicAdd(&mstats[threadIdx.x],
                  (double)(red[0][threadIdx.x] + red[1][threadIdx.x]
                         + red[2][threadIdx.x] + red[3][threadIdx.x]));
}

/* split fp32 -> bf16 hi (truncate) + bf16 lo (truncated remainder) */
__device__ __forceinline__ void bsplit(float g, short& hi, short& lo) {
    unsigned bits = __float_as_uint(g);
    unsigned hbits = bits & 0xFFFF0000u;
    float rem = g - __uint_as_float(hbits);
    hi = (short)(bits >> 16);
    lo = (short)(__float_as_uint(rem) >> 16);
}

/* ---------------- K5: main pass — u,v inline from pts4; split-bf16 MFMA -------- */
__global__ __launch_bounds__(256) void main_kernel(const int* __restrict__ idxb,
        const float4* __restrict__ pts4,
        const double* __restrict__ ms, const float* __restrict__ W1,
        const float* __restrict__ gamma1, const float* __restrict__ beta1,
        const float* __restrict__ W2,
        float* __restrict__ maxbuf, float* __restrict__ stats2f) {
    __shared__ __align__(16) short Thi[4][32*72];
    __shared__ __align__(16) short Tlo[4][32*72];
    __shared__ float chs[128];
    __shared__ float ab1s[128];
    const int tid = threadIdx.x;
    const int lane = tid & 63;
    const int wv = __builtin_amdgcn_readfirstlane(tid >> 6);
    const int l15 = lane & 15;
    const int quad = lane >> 4;
    if (tid < 128) chs[tid] = 0.f;
    if (tid < 64) {                                /* inline fin1m (bn1 affine) */
        int c = tid;
        double wu[3], wvv[3];
#pragma unroll
        for (int i = 0; i < 3; ++i) {
            wu[i] = (double)W1[c*6 + i];
            wvv[i] = (double)W1[c*6 + 3 + i] - wu[i];
        }
        const double S = (double)SAMPLES;
        double mean = (wu[0]*ms[0] + wu[1]*ms[1] + wu[2]*ms[2]
                     + 20.0*(wvv[0]*ms[3] + wvv[1]*ms[4] + wvv[2]*ms[5])) / S;
        double qM1 = wu[0]*wu[0]*ms[6] + wu[1]*wu[1]*ms[9] + wu[2]*wu[2]*ms[11]
                   + 2.0*(wu[0]*wu[1]*ms[7] + wu[0]*wu[2]*ms[8] + wu[1]*wu[2]*ms[10]);
        double cross = 0.0;
#pragma unroll
        for (int i = 0; i < 3; ++i)
#pragma unroll
            for (int j = 0; j < 3; ++j)
                cross += wu[i] * ms[12 + i*3 + j] * wvv[j];
        double qpp = wvv[0]*wvv[0]*ms[21] + wvv[1]*wvv[1]*ms[24] + wvv[2]*wvv[2]*ms[26]
                   + 2.0*(wvv[0]*wvv[1]*ms[22] + wvv[0]*wvv[2]*ms[23] + wvv[1]*wvv[2]*ms[25]);
        double e2 = (qM1 + 2.0*cross + 20.0*qpp) / S;
        double var = e2 - mean*mean;
        float a = (float)((double)gamma1[c] / sqrt(var + (double)EPSF));
        ab1s[c] = a;
        ab1s[64 + c] = beta1[c] - a * (float)mean;
    }
    __syncthreads();

    bf16x8 whi[8], wlo[8];
#pragma unroll
    for (int t = 0; t < 4; ++t)
#pragma unroll
    for (int f = 0; f < 2; ++f) {
        const int o = 16*t + l15;
        const int c0 = 32*f + quad*8;
        const float4* wr = (const float4*)(W2 + o*64 + c0);
        float4 w0 = wr[0], w1 = wr[1];
        float vals[8] = {w0.x,w0.y,w0.z,w0.w,w1.x,w1.y,w1.z,w1.w};
        bf16x8 h, l;
#pragma unroll
        for (int j = 0; j < 8; ++j) { short hj, lj; bsplit(vals[j], hj, lj); h[j]=hj; l[j]=lj; }
        whi[t*2+f] = h; wlo[t*2+f] = l;
    }

    const float w10 = W1[lane*6+0], w11 = W1[lane*6+1], w12 = W1[lane*6+2];
    const float w13 = W1[lane*6+3], w14 = W1[lane*6+4], w15 = W1[lane*6+5];
    const float a1 = ab1s[lane], b1 = ab1s[64 + lane];
    float ssum[4] = {0.f,0.f,0.f,0.f}, ssq[4] = {0.f,0.f,0.f,0.f};
    short* thi = &Thi[wv][0];
    short* tlo = &Tlo[wv][0];

    const int pt0 = (blockIdx.x * 4 + wv) * 4;
    const int b = pt0 >> 12;
    const float4* pb = pts4 + ((size_t)b << 12);

    for (int p = 0; p < 4; ++p) {
        const int pt = pt0 + p;
        const float4 pc = pb[pt & (NN - 1)];
        const float X = -0.5f*pc.x, Y = -0.5f*pc.y, Z = -0.5f*pc.z;
        const float vc = (w13 - w10)*X + (w14 - w11)*Y + (w15 - w12)*Z;
        const int* irow = idxb + (size_t)pt * KNN;
#pragma unroll
        for (int k = 0; k < KNN; ++k) {
            float4 pn = pb[irow[k]];
            float nx = -0.5f*pn.x, ny = -0.5f*pn.y, nz = -0.5f*pn.z;
            float uc = w10*nx + w11*ny + w12*nz;
            float g = a1 * (uc + vc) + b1;
            g = fmaxf(g, SLOPE * g);
            short hj, lj; bsplit(g, hj, lj);
            thi[k*72 + lane] = hj;
            tlo[k*72 + lane] = lj;
        }
        __builtin_amdgcn_wave_barrier();

        bf16x8 ah1[2], al1[2], ah2[2], al2[2];
#pragma unroll
        for (int f = 0; f < 2; ++f) {
            const int co = 32*f + quad*8;
            ah1[f] = *(const bf16x8*)&thi[l15*72 + co];
            al1[f] = *(const bf16x8*)&tlo[l15*72 + co];
            ah2[f] = *(const bf16x8*)&thi[(16 + l15)*72 + co];
            al2[f] = *(const bf16x8*)&tlo[(16 + l15)*72 + co];
        }

        f32x4 acc1[4], acc2[4];
#pragma unroll
        for (int t = 0; t < 4; ++t) { acc1[t] = (f32x4)0.f; acc2[t] = (f32x4)0.f; }
#pragma unroll
        for (int t = 0; t < 4; ++t) {
#pragma unroll
            for (int f = 0; f < 2; ++f) {
                acc1[t] = __builtin_amdgcn_mfma_f32_16x16x32_bf16(ah1[f], whi[t*2+f], acc1[t], 0,0,0);
                acc1[t] = __builtin_amdgcn_mfma_f32_16x16x32_bf16(al1[f], whi[t*2+f], acc1[t], 0,0,0);
                acc1[t] = __builtin_amdgcn_mfma_f32_16x16x32_bf16(ah1[f], wlo[t*2+f], acc1[t], 0,0,0);
                acc2[t] = __builtin_amdgcn_mfma_f32_16x16x32_bf16(ah2[f], whi[t*2+f], acc2[t], 0,0,0);
                acc2[t] = __builtin_amdgcn_mfma_f32_16x16x32_bf16(al2[f], whi[t*2+f], acc2[t], 0,0,0);
                acc2[t] = __builtin_amdgcn_mfma_f32_16x16x32_bf16(ah2[f], wlo[t*2+f], acc2[t], 0,0,0);
            }
        }
        __builtin_amdgcn_wave_barrier();

        const bool q0 = (quad == 0);
#pragma unroll
        for (int t = 0; t < 4; ++t) {
            float m1 = fmaxf(fmaxf(acc1[t][0], acc1[t][1]), fmaxf(acc1[t][2], acc1[t][3]));
            float s1 = acc1[t][0] + acc1[t][1] + acc1[t][2] + acc1[t][3];
            float q1 = acc1[t][0]*acc1[t][0] + acc1[t][1]*acc1[t][1]
                     + acc1[t][2]*acc1[t][2] + acc1[t][3]*acc1[t][3];
            float m2 = fmaxf(fmaxf(acc2[t][0], acc2[t][1]), fmaxf(acc2[t][2], acc2[t][3]));
            float s2 = acc2[t][0] + acc2[t][1] + acc2[t][2] + acc2[t][3];
            float q2 = acc2[t][0]*acc2[t][0] + acc2[t][1]*acc2[t][1]
                     + acc2[t][2]*acc2[t][2] + acc2[t][3]*acc2[t][3];
            float lm = q0 ? fmaxf(m1, m2) : m1;
            float ls = q0 ? (s1 + s2) : s1;
            float lq = q0 ? (q1 + q2) : q1;
            lm = fmaxf(lm, __shfl_xor(lm, 16)); lm = fmaxf(lm, __shfl_xor(lm, 32));
            ls += __shfl_xor(ls, 16); ls += __shfl_xor(ls, 32);
            lq += __shfl_xor(lq, 16); lq += __shfl_xor(lq, 32);
            if (q0) maxbuf[((size_t)pt << 6) + 16*t + l15] = lm;
            ssum[t] += ls; ssq[t] += lq;
        }
    }

    if (quad == 0) {
#pragma unroll
        for (int t = 0; t < 4; ++t) {
            atomicAdd(&chs[16*t + l15], ssum[t]);
            atomicAdd(&chs[64 + 16*t + l15], ssq[t]);
        }
    }
    __syncthreads();
    if (tid < 128)
        atomicAdd(&stats2f[(blockIdx.x & 1)*128 + tid], chs[tid]);
}

/* ---------------- K7: epilogue — fin2 inlined; transpose + bn2 + lrelu --------- */
__global__ __launch_bounds__(256) void out_kernel(const float* __restrict__ maxbuf,
        const float* __restrict__ s2f, const float* __restrict__ gamma2,
        const float* __restrict__ beta2, float* __restrict__ out) {
    __shared__ float t[64][65];
    __shared__ float ab2s[128];
    const int tid = threadIdx.x;
    if (tid < 64) {                                /* inline fin2 */
        int o = tid;
        double sum = (double)s2f[o] + (double)s2f[128 + o];
        double sq  = (double)s2f[64 + o] + (double)s2f[192 + o];
        double cnt = (double)SAMPLES;
        double mean = sum / cnt;
        double var  = sq / cnt - mean*mean;
        float a = (float)((double)gamma2[o] / sqrt(var + (double)EPSF));
        ab2s[o] = a;
        ab2s[64 + o] = beta2[o] - a * (float)mean;
    }
    const int b = blockIdx.x >> 6;
    const int n0 = (blockIdx.x & 63) << 6;
#pragma unroll
    for (int i = 0; i < 16; ++i) {
        int r = (tid >> 6) + i*4;
        int c = tid & 63;
        t[r][c] = maxbuf[(((size_t)((b << 12) + n0 + r)) << 6) + c];
    }
    __syncthreads();
#pragma unroll
    for (int i = 0; i < 16; ++i) {
        int o = (tid >> 6) + i*4;
        int nn = tid & 63;
        float a = ab2s[o], bb = ab2s[64 + o];
        float h = a * t[nn][o] + bb;
        out[(((size_t)(b*64 + o)) << 12) + n0 + nn] = h >= 0.f ? h : SLOPE*h;
    }
}

extern "C" void kernel_launch(void* const* d_in, const int* in_sizes, int n_in,
                              void* d_out, int out_size, void* d_ws, size_t ws_size,
                              hipStream_t stream) {
    const float* x      = (const float*)d_in[0];
    const float* W1     = (const float*)d_in[1];
    const float* gamma1 = (const float*)d_in[2];
    const float* beta1  = (const float*)d_in[3];
    const float* W2     = (const float*)d_in[4];
    const float* gamma2 = (const float*)d_in[5];
    const float* beta2  = (const float*)d_in[6];
    float* out = (float*)d_out;

    char* ws = (char*)d_ws;
    int*    idxb    = (int*)   (ws + 0);           /* 2,621,440 B */
    float4* pts4    = (float4*)(ws + 2621440);     /* 512 KB */
    float4* sp4     = (float4*)(ws + 3145728);     /* 512 KB sorted pts */
    int*    sidx    = (int*)   (ws + 3670016);     /* 128 KB sorted->orig */
    int*    rankArr = (int*)   (ws + 3801088);     /* 128 KB orig->sorted */
    float*  maxbuf  = (float*) (ws + 19398656);    /* 8,388,608 B, (b,n,o) */
    double* mstats  = (double*)(ws + 27787264);    /* 27 doubles */
    float*  stats2f = (float*) (ws + 27787520);    /* 2x128 floats */
    float2* zbuf    = (float2*)(ws + 27787264);    /* zero region */

    pts4_kernel   <<<128, 256, 0, stream>>>(x, pts4, zbuf);
    sort_kernel   <<<8, 1024, 0, stream>>>(pts4, sp4, sidx, rankArr);
    knn_kernel    <<<8192, 256, 0, stream>>>(pts4, sp4, sidx, rankArr, idxb);
    moments_kernel<<<128, 256, 0, stream>>>(pts4, idxb, mstats);
    main_kernel   <<<2048, 256, 0, stream>>>(idxb, pts4, mstats, W1, gamma1, beta1,
                                             W2, maxbuf, stats2f);
    out_kernel    <<<512, 256, 0, stream>>>(maxbuf, stats2f, gamma2, beta2, out);
}

// Round 12
// 263.713 us; speedup vs baseline: 1.6532x; 1.0202x over previous
//
#include <hip/hip_runtime.h>
#include <hip/hip_bf16.h>
#include <math.h>

#define BB 8
#define NN 4096
#define KNN 20
#define CH 64
#define SAMPLES (BB*NN*KNN)   /* 655360 */
#define EPSF 1e-5f
#define SLOPE 0.2f
#define MCOPY 32              /* mstats copies to spread atomic contention */

typedef float f32x4 __attribute__((ext_vector_type(4)));
typedef short bf16x8 __attribute__((ext_vector_type(8)));

/* decode order-preserving uint back to float */
__device__ __forceinline__ float key_decode(unsigned e) {
    return __uint_as_float((e & 0x80000000u) ? (e ^ 0x80000000u) : ~e);
}

/* rank-select flush: merge ovf[0..cnt) + inc[0..19] -> new exact top-20 in inc. */
__device__ __forceinline__ void rank_flush(unsigned long long* ovf,
                                           unsigned long long* inc,
                                           unsigned long long* scr,
                                           int& cnt, float& kthd, int lane) {
    while (cnt > 0) {
        int take = cnt < 44 ? cnt : 44;
        unsigned long long key;
        if (lane < take)      key = ovf[cnt - take + lane];
        else if (lane >= 44)  key = inc[lane - 44];
        else                  key = ~0ull;
        scr[lane] = key;
        __builtin_amdgcn_wave_barrier();
        int r = 0;
#pragma unroll
        for (int t = 0; t < 64; ++t) {
            unsigned long long kt = scr[t];       /* uniform addr -> broadcast */
            r += (kt < key) ? 1 : 0;
        }
        __builtin_amdgcn_wave_barrier();
        if (r < KNN) inc[r] = key;                /* padding ranks land >= 20 */
        __builtin_amdgcn_wave_barrier();
        kthd = key_decode((unsigned)(inc[KNN-1] >> 32));
        cnt -= take;
    }
}

/* ---------------- K0: per-batch: build pts4 + bitonic sort by x + zero stats --- */
__global__ __launch_bounds__(1024) void sort_kernel(const float* __restrict__ x,
        float4* __restrict__ pts4, float4* __restrict__ sp4, int* __restrict__ sidx,
        double* __restrict__ zreg) {
#pragma clang fp contract(off)
    __shared__ unsigned long long S[NN];                     /* 32 KB */
    const int tid = threadIdx.x;
    const int b = blockIdx.x;
    if (b == 0 && tid < 992) zreg[tid] = 0.0;     /* mstats(864d) + stats2f(128d) */
    const float* xb = x + (size_t)b * 3 * NN;
    for (int i = tid; i < NN; i += 1024) {
        float mx = xb[i], my = xb[NN + i], mz = xb[2*NN + i];
        float sq = mx*mx; sq += my*my; sq += mz*mz;          /* ref summation order */
        pts4[(b << 12) + i] = make_float4(-2.0f*mx, -2.0f*my, -2.0f*mz, sq);
        unsigned uu = __float_as_uint(mx);
        unsigned e = uu ^ (((unsigned)((int)uu >> 31)) | 0x80000000u);
        S[i] = ((unsigned long long)e << 32) | (unsigned)i;
    }
    __syncthreads();
    for (int k = 2; k <= NN; k <<= 1) {
        for (int j = k >> 1; j > 0; j >>= 1) {
#pragma unroll
            for (int tt = 0; tt < 2; ++tt) {
                int t = tid + tt*1024;            /* 2048 pairs */
                int i = ((t & ~(j - 1)) << 1) | (t & (j - 1));
                int h = i | j;
                unsigned long long a = S[i], c = S[h];
                bool up = ((i & k) == 0);
                if ((a > c) == up) { S[i] = c; S[h] = a; }
            }
            __syncthreads();
        }
    }
    for (int s = tid; s < NN; s += 1024) {
        int oi = (int)(unsigned)(S[s] & 0xFFFFFFFFu);
        float mx = xb[oi], my = xb[NN + oi], mz = xb[2*NN + oi];  /* recompute: no RAW */
        float sq = mx*mx; sq += my*my; sq += mz*mz;
        sp4[(b << 12) + s] = make_float4(-2.0f*mx, -2.0f*my, -2.0f*mz, sq);
        sidx[(b << 12) + s] = oi;
    }
}

/* ---------------- K1: exact KNN — sorted-order queries + moments epilogue ------ */
__global__ __launch_bounds__(256) void knn_kernel(const float4* __restrict__ pts4,
        const float4* __restrict__ sp4, const int* __restrict__ sidx,
        int* __restrict__ idx_out, double* __restrict__ mstats) {
#pragma clang fp contract(off)
    __shared__ unsigned long long OVF[4][96];
    __shared__ unsigned long long INC[4][24];
    __shared__ unsigned long long SCR[4][64];
    __shared__ float MOM[4][27];
    const int tid = threadIdx.x;
    const int lane = tid & 63;
    const int wv = __builtin_amdgcn_readfirstlane(tid >> 6);
    const int s = blockIdx.x * 4 + wv;                       /* sorted-rank query */
    const int b = s >> 12;
    const int ss = s & (NN - 1);
    const float4* sb = sp4 + ((size_t)b << 12);
    const int* si = sidx + ((size_t)b << 12);
    unsigned long long* ovf = &OVF[wv][0];
    unsigned long long* inc = &INC[wv][0];
    unsigned long long* scr = &SCR[wv][0];

    const float4 Qc = sb[ss];
    const float qx = -0.5f*Qc.x, qy = -0.5f*Qc.y, qz = -0.5f*Qc.z; /* exact coords */
    const float sqn = Qc.w;
    int c0 = ss - 32; c0 = c0 < 0 ? 0 : (c0 > NN-64 ? NN-64 : c0);
    float kthd, thr, M;
    int cnt = 0;

    /* prefill: exact d for the 64 nearest-in-x, rank-select directly */
    {
        const float4 P = sb[c0 + lane];
        const float mx = -0.5f*P.x, my = -0.5f*P.y, mz = -0.5f*P.z;
        float inner = qx*mx; inner += qy*my; inner += qz*mz;
        const float d = (sqn - 2.0f*inner) + P.w;            /* ref parenthesization */
        unsigned uu = __float_as_uint(d);
        unsigned e = uu ^ (((unsigned)((int)uu >> 31)) | 0x80000000u);
        unsigned long long key = ((unsigned long long)e << 32) | (unsigned)si[c0 + lane];
        scr[lane] = key;
        __builtin_amdgcn_wave_barrier();
        int r = 0;
#pragma unroll
        for (int t = 0; t < 64; ++t) {
            unsigned long long kt = scr[t];
            r += (kt < key) ? 1 : 0;
        }
        __builtin_amdgcn_wave_barrier();
        if (r < KNN) inc[r] = key;
        __builtin_amdgcn_wave_barrier();
        kthd = key_decode((unsigned)(inc[KNN-1] >> 32));
        M = 1e-3f*(fabsf(kthd) + fabsf(sqn) + 1.0f);
        thr = (kthd - sqn) + M;
    }

    int lo = c0, hi = c0 + 64;
    bool dl = (lo == 0), dr = (hi == NN);

    while (!dl || !dr) {
        if (!dl) {
            const float xb2 = -0.5f*sb[lo-1].x;
            const float dx = qx - xb2;
            if (dx*dx > kthd + M) dl = true;
            else {
                if (cnt > 32) {
                    rank_flush(ovf, inc, scr, cnt, kthd, lane);
                    M = 1e-3f*(fabsf(kthd) + fabsf(sqn) + 1.0f);
                    thr = (kthd - sqn) + M;
                }
                int st = lo - 64; if (st < 0) st = 0;
                const int sI = st + lane;
                const bool valid = sI < lo;
                const float4 P = sb[sI];
                const float sc = fmaf(P.x, qx, fmaf(P.y, qy, fmaf(P.z, qz, P.w)));
                bool push = valid && (sc <= thr);
                unsigned long long mask = __ballot(push);
                if (mask) {
                    if (push) {
                        const float mx = -0.5f*P.x, my = -0.5f*P.y, mz = -0.5f*P.z;
                        float inner = qx*mx; inner += qy*my; inner += qz*mz;
                        const float d = (sqn - 2.0f*inner) + P.w;
                        unsigned uu = __float_as_uint(d);
                        unsigned e = uu ^ (((unsigned)((int)uu >> 31)) | 0x80000000u);
                        unsigned long long key = ((unsigned long long)e << 32) | (unsigned)si[sI];
                        int ofs = (int)__popcll(mask & ((1ull << lane) - 1ull));
                        ovf[cnt + ofs] = key;
                    }
                    cnt += (int)__popcll(mask);
                }
                lo = st;
                dl = (lo == 0);
            }
        }
        if (!dr) {
            const float xb2 = -0.5f*sb[hi].x;
            const float dx = xb2 - qx;
            if (dx*dx > kthd + M) dr = true;
            else {
                if (cnt > 32) {
                    rank_flush(ovf, inc, scr, cnt, kthd, lane);
                    M = 1e-3f*(fabsf(kthd) + fabsf(sqn) + 1.0f);
                    thr = (kthd - sqn) + M;
                }
                int en = hi + 64; if (en > NN) en = NN;
                const int sI = hi + lane;
                const int sa = sI < NN-1 ? sI : NN-1;
                const bool valid = sI < en;
                const float4 P = sb[sa];
                const float sc = fmaf(P.x, qx, fmaf(P.y, qy, fmaf(P.z, qz, P.w)));
                bool push = valid && (sc <= thr);
                unsigned long long mask = __ballot(push);
                if (mask) {
                    if (push) {
                        const float mx = -0.5f*P.x, my = -0.5f*P.y, mz = -0.5f*P.z;
                        float inner = qx*mx; inner += qy*my; inner += qz*mz;
                        const float d = (sqn - 2.0f*inner) + P.w;
                        unsigned uu = __float_as_uint(d);
                        unsigned e = uu ^ (((unsigned)((int)uu >> 31)) | 0x80000000u);
                        unsigned long long key = ((unsigned long long)e << 32) | (unsigned)si[sa];
                        int ofs = (int)__popcll(mask & ((1ull << lane) - 1ull));
                        ovf[cnt + ofs] = key;
                    }
                    cnt += (int)__popcll(mask);
                }
                hi = en;
                dr = (hi == NN);
            }
        }
    }
    rank_flush(ovf, inc, scr, cnt, kthd, lane);

    const int orig = si[ss];
    if (lane < KNN)
        idx_out[(size_t)((b << 12) + orig) * KNN + lane] =
            (int)(unsigned)(inc[lane] & 0xFFFFFFFFull);

    /* moments epilogue: lanes 0..19 gather the 20 neighbors, 9 reductions */
    float nx = 0.f, ny = 0.f, nz = 0.f, xx = 0.f, xy = 0.f, xz = 0.f,
          yy = 0.f, yz = 0.f, zz = 0.f;
    if (lane < KNN) {
        int nbr = (int)(unsigned)(inc[lane] & 0xFFFFFFFFull);
        float4 pn = pts4[(b << 12) + nbr];
        nx = -0.5f*pn.x; ny = -0.5f*pn.y; nz = -0.5f*pn.z;
        xx = nx*nx; xy = nx*ny; xz = nx*nz; yy = ny*ny; yz = ny*nz; zz = nz*nz;
    }
#pragma unroll
    for (int off = 32; off > 0; off >>= 1) {
        nx += __shfl_xor(nx, off); ny += __shfl_xor(ny, off); nz += __shfl_xor(nz, off);
        xx += __shfl_xor(xx, off); xy += __shfl_xor(xy, off); xz += __shfl_xor(xz, off);
        yy += __shfl_xor(yy, off); yz += __shfl_xor(yz, off); zz += __shfl_xor(zz, off);
    }
    if (lane == 0) {
        MOM[wv][0] = nx;  MOM[wv][1] = ny;  MOM[wv][2] = nz;
        MOM[wv][3] = qx;  MOM[wv][4] = qy;  MOM[wv][5] = qz;
        MOM[wv][6] = xx;  MOM[wv][7] = xy;  MOM[wv][8] = xz;
        MOM[wv][9] = yy;  MOM[wv][10] = yz; MOM[wv][11] = zz;
        MOM[wv][12] = nx*qx; MOM[wv][13] = nx*qy; MOM[wv][14] = nx*qz;
        MOM[wv][15] = ny*qx; MOM[wv][16] = ny*qy; MOM[wv][17] = ny*qz;
        MOM[wv][18] = nz*qx; MOM[wv][19] = nz*qy; MOM[wv][20] = nz*qz;
        MOM[wv][21] = qx*qx; MOM[wv][22] = qx*qy; MOM[wv][23] = qx*qz;
        MOM[wv][24] = qy*qy; MOM[wv][25] = qy*qz; MOM[wv][26] = qz*qz;
    }
    __syncthreads();
    if (tid < 27)
        atomicAdd(&mstats[(blockIdx.x & (MCOPY-1))*27 + tid],
                  (double)(MOM[0][tid] + MOM[1][tid] + MOM[2][tid] + MOM[3][tid]));
}

/* split fp32 -> bf16 hi (truncate) + bf16 lo (truncated remainder) */
__device__ __forceinline__ void bsplit(float g, short& hi, short& lo) {
    unsigned bits = __float_as_uint(g);
    unsigned hbits = bits & 0xFFFF0000u;
    float rem = g - __uint_as_float(hbits);
    hi = (short)(bits >> 16);
    lo = (short)(__float_as_uint(rem) >> 16);
}

/* ---------------- K5: main pass — u,v inline from pts4; split-bf16 MFMA -------- */
__global__ __launch_bounds__(256) void main_kernel(const int* __restrict__ idxb,
        const float4* __restrict__ pts4,
        const double* __restrict__ ms, const float* __restrict__ W1,
        const float* __restrict__ gamma1, const float* __restrict__ beta1,
        const float* __restrict__ W2,
        float* __restrict__ maxbuf, float* __restrict__ stats2f) {
    __shared__ __align__(16) short Thi[4][32*72];
    __shared__ __align__(16) short Tlo[4][32*72];
    __shared__ float chs[128];
    __shared__ float ab1s[128];
    __shared__ double msd[27];
    const int tid = threadIdx.x;
    const int lane = tid & 63;
    const int wv = __builtin_amdgcn_readfirstlane(tid >> 6);
    const int l15 = lane & 15;
    const int quad = lane >> 4;
    if (tid < 128) chs[tid] = 0.f;
    if (tid < 27) {                                /* sum the 32 mstats copies */
        double t = 0.0;
        for (int c = 0; c < MCOPY; ++c) t += ms[c*27 + tid];
        msd[tid] = t;
    }
    __syncthreads();
    if (tid < 64) {                                /* inline fin1m (bn1 affine) */
        int c = tid;
        double wu[3], wvv[3];
#pragma unroll
        for (int i = 0; i < 3; ++i) {
            wu[i] = (double)W1[c*6 + i];
            wvv[i] = (double)W1[c*6 + 3 + i] - wu[i];
        }
        const double S = (double)SAMPLES;
        double mean = (wu[0]*msd[0] + wu[1]*msd[1] + wu[2]*msd[2]
                     + 20.0*(wvv[0]*msd[3] + wvv[1]*msd[4] + wvv[2]*msd[5])) / S;
        double qM1 = wu[0]*wu[0]*msd[6] + wu[1]*wu[1]*msd[9] + wu[2]*wu[2]*msd[11]
                   + 2.0*(wu[0]*wu[1]*msd[7] + wu[0]*wu[2]*msd[8] + wu[1]*wu[2]*msd[10]);
        double cross = 0.0;
#pragma unroll
        for (int i = 0; i < 3; ++i)
#pragma unroll
            for (int j = 0; j < 3; ++j)
                cross += wu[i] * msd[12 + i*3 + j] * wvv[j];
        double qpp = wvv[0]*wvv[0]*msd[21] + wvv[1]*wvv[1]*msd[24] + wvv[2]*wvv[2]*msd[26]
                   + 2.0*(wvv[0]*wvv[1]*msd[22] + wvv[0]*wvv[2]*msd[23] + wvv[1]*wvv[2]*msd[25]);
        double e2 = (qM1 + 2.0*cross + 20.0*qpp) / S;
        double var = e2 - mean*mean;
        float a = (float)((double)gamma1[c] / sqrt(var + (double)EPSF));
        ab1s[c] = a;
        ab1s[64 + c] = beta1[c] - a * (float)mean;
    }
    __syncthreads();

    bf16x8 whi[8], wlo[8];
#pragma unroll
    for (int t = 0; t < 4; ++t)
#pragma unroll
    for (int f = 0; f < 2; ++f) {
        const int o = 16*t + l15;
        const int c0 = 32*f + quad*8;
        const float4* wr = (const float4*)(W2 + o*64 + c0);
        float4 w0 = wr[0], w1 = wr[1];
        float vals[8] = {w0.x,w0.y,w0.z,w0.w,w1.x,w1.y,w1.z,w1.w};
        bf16x8 h, l;
#pragma unroll
        for (int j = 0; j < 8; ++j) { short hj, lj; bsplit(vals[j], hj, lj); h[j]=hj; l[j]=lj; }
        whi[t*2+f] = h; wlo[t*2+f] = l;
    }

    const float w10 = W1[lane*6+0], w11 = W1[lane*6+1], w12 = W1[lane*6+2];
    const float w13 = W1[lane*6+3], w14 = W1[lane*6+4], w15 = W1[lane*6+5];
    const float a1 = ab1s[lane], b1 = ab1s[64 + lane];
    float ssum[4] = {0.f,0.f,0.f,0.f}, ssq[4] = {0.f,0.f,0.f,0.f};
    short* thi = &Thi[wv][0];
    short* tlo = &Tlo[wv][0];

    const int pt0 = (blockIdx.x * 4 + wv) * 4;
    const int b = pt0 >> 12;
    const float4* pb = pts4 + ((size_t)b << 12);

    for (int p = 0; p < 4; ++p) {
        const int pt = pt0 + p;
        const float4 pc = pb[pt & (NN - 1)];
        const float X = -0.5f*pc.x, Y = -0.5f*pc.y, Z = -0.5f*pc.z;
        const float vc = (w13 - w10)*X + (w14 - w11)*Y + (w15 - w12)*Z;
        const int* irow = idxb + (size_t)pt * KNN;
#pragma unroll
        for (int k = 0; k < KNN; ++k) {
            float4 pn = pb[irow[k]];
            float nx = -0.5f*pn.x, ny = -0.5f*pn.y, nz = -0.5f*pn.z;
            float uc = w10*nx + w11*ny + w12*nz;
            float g = a1 * (uc + vc) + b1;
            g = fmaxf(g, SLOPE * g);
            short hj, lj; bsplit(g, hj, lj);
            thi[k*72 + lane] = hj;
            tlo[k*72 + lane] = lj;
        }
        __builtin_amdgcn_wave_barrier();

        bf16x8 ah1[2], al1[2], ah2[2], al2[2];
#pragma unroll
        for (int f = 0; f < 2; ++f) {
            const int co = 32*f + quad*8;
            ah1[f] = *(const bf16x8*)&thi[l15*72 + co];
            al1[f] = *(const bf16x8*)&tlo[l15*72 + co];
            ah2[f] = *(const bf16x8*)&thi[(16 + l15)*72 + co];
            al2[f] = *(const bf16x8*)&tlo[(16 + l15)*72 + co];
        }

        f32x4 acc1[4], acc2[4];
#pragma unroll
        for (int t = 0; t < 4; ++t) { acc1[t] = (f32x4)0.f; acc2[t] = (f32x4)0.f; }
#pragma unroll
        for (int t = 0; t < 4; ++t) {
#pragma unroll
            for (int f = 0; f < 2; ++f) {
                acc1[t] = __builtin_amdgcn_mfma_f32_16x16x32_bf16(ah1[f], whi[t*2+f], acc1[t], 0,0,0);
                acc1[t] = __builtin_amdgcn_mfma_f32_16x16x32_bf16(al1[f], whi[t*2+f], acc1[t], 0,0,0);
                acc1[t] = __builtin_amdgcn_mfma_f32_16x16x32_bf16(ah1[f], wlo[t*2+f], acc1[t], 0,0,0);
                acc2[t] = __builtin_amdgcn_mfma_f32_16x16x32_bf16(ah2[f], whi[t*2+f], acc2[t], 0,0,0);
                acc2[t] = __builtin_amdgcn_mfma_f32_16x16x32_bf16(al2[f], whi[t*2+f], acc2[t], 0,0,0);
                acc2[t] = __builtin_amdgcn_mfma_f32_16x16x32_bf16(ah2[f], wlo[t*2+f], acc2[t], 0,0,0);
            }
        }
        __builtin_amdgcn_wave_barrier();

        const bool q0 = (quad == 0);
#pragma unroll
        for (int t = 0; t < 4; ++t) {
            float m1 = fmaxf(fmaxf(acc1[t][0], acc1[t][1]), fmaxf(acc1[t][2], acc1[t][3]));
            float s1 = acc1[t][0] + acc1[t][1] + acc1[t][2] + acc1[t][3];
            float q1 = acc1[t][0]*acc1[t][0] + acc1[t][1]*acc1[t][1]
                     + acc1[t][2]*acc1[t][2] + acc1[t][3]*acc1[t][3];
            float m2 = fmaxf(fmaxf(acc2[t][0], acc2[t][1]), fmaxf(acc2[t][2], acc2[t][3]));
            float s2 = acc2[t][0] + acc2[t][1] + acc2[t][2] + acc2[t][3];
            float q2 = acc2[t][0]*acc2[t][0] + acc2[t][1]*acc2[t][1]
                     + acc2[t][2]*acc2[t][2] + acc2[t][3]*acc2[t][3];
            float lm = q0 ? fmaxf(m1, m2) : m1;
            float ls = q0 ? (s1 + s2) : s1;
            float lq = q0 ? (q1 + q2) : q1;
            lm = fmaxf(lm, __shfl_xor(lm, 16)); lm = fmaxf(lm, __shfl_xor(lm, 32));
            ls += __shfl_xor(ls, 16); ls += __shfl_xor(ls, 32);
            lq += __shfl_xor(lq, 16); lq += __shfl_xor(lq, 32);
            if (q0) maxbuf[((size_t)pt << 6) + 16*t + l15] = lm;
            ssum[t] += ls; ssq[t] += lq;
        }
    }

    if (quad == 0) {
#pragma unroll
        for (int t = 0; t < 4; ++t) {
            atomicAdd(&chs[16*t + l15], ssum[t]);
            atomicAdd(&chs[64 + 16*t + l15], ssq[t]);
        }
    }
    __syncthreads();
    if (tid < 128)
        atomicAdd(&stats2f[(blockIdx.x & 1)*128 + tid], chs[tid]);
}

/* ---------------- K7: epilogue — fin2 inlined; transpose + bn2 + lrelu --------- */
__global__ __launch_bounds__(256) void out_kernel(const float* __restrict__ maxbuf,
        const float* __restrict__ s2f, const float* __restrict__ gamma2,
        const float* __restrict__ beta2, float* __restrict__ out) {
    __shared__ float t[64][65];
    __shared__ float ab2s[128];
    const int tid = threadIdx.x;
    if (tid < 64) {                                /* inline fin2 */
        int o = tid;
        double sum = (double)s2f[o] + (double)s2f[128 + o];
        double sq  = (double)s2f[64 + o] + (double)s2f[192 + o];
        double cnt = (double)SAMPLES;
        double mean = sum / cnt;
        double var  = sq / cnt - mean*mean;
        float a = (float)((double)gamma2[o] / sqrt(var + (double)EPSF));
        ab2s[o] = a;
        ab2s[64 + o] = beta2[o] - a * (float)mean;
    }
    const int b = blockIdx.x >> 6;
    const int n0 = (blockIdx.x & 63) << 6;
#pragma unroll
    for (int i = 0; i < 16; ++i) {
        int r = (tid >> 6) + i*4;
        int c = tid & 63;
        t[r][c] = maxbuf[(((size_t)((b << 12) + n0 + r)) << 6) + c];
    }
    __syncthreads();
#pragma unroll
    for (int i = 0; i < 16; ++i) {
        int o = (tid >> 6) + i*4;
        int nn = tid & 63;
        float a = ab2s[o], bb = ab2s[64 + o];
        float h = a * t[nn][o] + bb;
        out[(((size_t)(b*64 + o)) << 12) + n0 + nn] = h >= 0.f ? h : SLOPE*h;
    }
}

extern "C" void kernel_launch(void* const* d_in, const int* in_sizes, int n_in,
                              void* d_out, int out_size, void* d_ws, size_t ws_size,
                              hipStream_t stream) {
    const float* x      = (const float*)d_in[0];
    const float* W1     = (const float*)d_in[1];
    const float* gamma1 = (const float*)d_in[2];
    const float* beta1  = (const float*)d_in[3];
    const float* W2     = (const float*)d_in[4];
    const float* gamma2 = (const float*)d_in[5];
    const float* beta2  = (const float*)d_in[6];
    float* out = (float*)d_out;

    char* ws = (char*)d_ws;
    int*    idxb    = (int*)   (ws + 0);           /* 2,621,440 B */
    float4* pts4    = (float4*)(ws + 2621440);     /* 512 KB */
    float4* sp4     = (float4*)(ws + 3145728);     /* 512 KB sorted pts */
    int*    sidx    = (int*)   (ws + 3670016);     /* 128 KB sorted->orig */
    float*  maxbuf  = (float*) (ws + 19398656);    /* 8,388,608 B, (b,n,o) */
    double* mstats  = (double*)(ws + 27787264);    /* 32x27 doubles = 6912 B */
    float*  stats2f = (float*) (ws + 27794176);    /* 2x128 floats = 1024 B */
    double* zreg    = (double*)(ws + 27787264);    /* zero region: 992 doubles */

    sort_kernel <<<8, 1024, 0, stream>>>(x, pts4, sp4, sidx, zreg);
    knn_kernel  <<<8192, 256, 0, stream>>>(pts4, sp4, sidx, idxb, mstats);
    main_kernel <<<2048, 256, 0, stream>>>(idxb, pts4, mstats, W1, gamma1, beta1,
                                           W2, maxbuf, stats2f);
    out_kernel  <<<512, 256, 0, stream>>>(maxbuf, stats2f, gamma2, beta2, out);
}

// Round 13
// 258.463 us; speedup vs baseline: 1.6868x; 1.0203x over previous
//
#include <hip/hip_runtime.h>
#include <hip/hip_bf16.h>
#include <math.h>

#define BB 8
#define NN 4096
#define KNN 20
#define CH 64
#define SAMPLES (BB*NN*KNN)   /* 655360 */
#define EPSF 1e-5f
#define SLOPE 0.2f
#define MCOPY 32              /* mstats copies to spread atomic contention */

typedef float f32x4 __attribute__((ext_vector_type(4)));
typedef short bf16x8 __attribute__((ext_vector_type(8)));

/* decode order-preserving uint back to float */
__device__ __forceinline__ float key_decode(unsigned e) {
    return __uint_as_float((e & 0x80000000u) ? (e ^ 0x80000000u) : ~e);
}

/* rank-select flush: merge ovf[0..cnt) + inc[0..19] -> new exact top-20 in inc. */
__device__ __forceinline__ void rank_flush(unsigned long long* ovf,
                                           unsigned long long* inc,
                                           unsigned long long* scr,
                                           int& cnt, float& kthd, int lane) {
    while (cnt > 0) {
        int take = cnt < 44 ? cnt : 44;
        unsigned long long key;
        if (lane < take)      key = ovf[cnt - take + lane];
        else if (lane >= 44)  key = inc[lane - 44];
        else                  key = ~0ull;
        scr[lane] = key;
        __builtin_amdgcn_wave_barrier();
        int r = 0;
#pragma unroll
        for (int t = 0; t < 64; ++t) {
            unsigned long long kt = scr[t];       /* uniform addr -> broadcast */
            r += (kt < key) ? 1 : 0;
        }
        __builtin_amdgcn_wave_barrier();
        if (r < KNN) inc[r] = key;                /* padding ranks land >= 20 */
        __builtin_amdgcn_wave_barrier();
        kthd = key_decode((unsigned)(inc[KNN-1] >> 32));
        cnt -= take;
    }
}

/* ---------------- K0: per-batch: build pts4 + bitonic sort by x + zero stats --- */
__global__ __launch_bounds__(1024) void sort_kernel(const float* __restrict__ x,
        float4* __restrict__ pts4, float4* __restrict__ sp4, int* __restrict__ sidx,
        int* __restrict__ rankArr, double* __restrict__ zreg) {
#pragma clang fp contract(off)
    __shared__ unsigned long long S[NN];                     /* 32 KB */
    const int tid = threadIdx.x;
    const int b = blockIdx.x;
    if (b == 0 && tid < 992) zreg[tid] = 0.0;     /* mstats(864d) + stats2f(128d) */
    const float* xb = x + (size_t)b * 3 * NN;
    for (int i = tid; i < NN; i += 1024) {
        float mx = xb[i], my = xb[NN + i], mz = xb[2*NN + i];
        float sq = mx*mx; sq += my*my; sq += mz*mz;          /* ref summation order */
        pts4[(b << 12) + i] = make_float4(-2.0f*mx, -2.0f*my, -2.0f*mz, sq);
        unsigned uu = __float_as_uint(mx);
        unsigned e = uu ^ (((unsigned)((int)uu >> 31)) | 0x80000000u);
        S[i] = ((unsigned long long)e << 32) | (unsigned)i;
    }
    __syncthreads();
    for (int k = 2; k <= NN; k <<= 1) {
        for (int j = k >> 1; j > 0; j >>= 1) {
#pragma unroll
            for (int tt = 0; tt < 2; ++tt) {
                int t = tid + tt*1024;            /* 2048 pairs */
                int i = ((t & ~(j - 1)) << 1) | (t & (j - 1));
                int h = i | j;
                unsigned long long a = S[i], c = S[h];
                bool up = ((i & k) == 0);
                if ((a > c) == up) { S[i] = c; S[h] = a; }
            }
            __syncthreads();
        }
    }
    for (int s = tid; s < NN; s += 1024) {
        int oi = (int)(unsigned)(S[s] & 0xFFFFFFFFu);
        float mx = xb[oi], my = xb[NN + oi], mz = xb[2*NN + oi];  /* recompute: no RAW */
        float sq = mx*mx; sq += my*my; sq += mz*mz;
        sp4[(b << 12) + s] = make_float4(-2.0f*mx, -2.0f*my, -2.0f*mz, sq);
        sidx[(b << 12) + s] = oi;
        rankArr[(b << 12) + oi] = s;
    }
}

/* ---------------- K1: exact KNN — sorted-order queries + moments epilogue.
   idx_out written at SORTED rank (coalesced); main reads via rankArr. --------- */
__global__ __launch_bounds__(256) void knn_kernel(const float4* __restrict__ pts4,
        const float4* __restrict__ sp4, const int* __restrict__ sidx,
        int* __restrict__ idx_out, double* __restrict__ mstats) {
#pragma clang fp contract(off)
    __shared__ unsigned long long OVF[4][96];
    __shared__ unsigned long long INC[4][24];
    __shared__ unsigned long long SCR[4][64];
    __shared__ float MOM[4][27];
    const int tid = threadIdx.x;
    const int lane = tid & 63;
    const int wv = __builtin_amdgcn_readfirstlane(tid >> 6);
    const int s = blockIdx.x * 4 + wv;                       /* sorted-rank query */
    const int b = s >> 12;
    const int ss = s & (NN - 1);
    const float4* sb = sp4 + ((size_t)b << 12);
    const int* si = sidx + ((size_t)b << 12);
    unsigned long long* ovf = &OVF[wv][0];
    unsigned long long* inc = &INC[wv][0];
    unsigned long long* scr = &SCR[wv][0];

    const float4 Qc = sb[ss];
    const float qx = -0.5f*Qc.x, qy = -0.5f*Qc.y, qz = -0.5f*Qc.z; /* exact coords */
    const float sqn = Qc.w;
    int c0 = ss - 32; c0 = c0 < 0 ? 0 : (c0 > NN-64 ? NN-64 : c0);
    float kthd, thr, M;
    int cnt = 0;

    /* prefill: exact d for the 64 nearest-in-x, rank-select directly */
    {
        const float4 P = sb[c0 + lane];
        const float mx = -0.5f*P.x, my = -0.5f*P.y, mz = -0.5f*P.z;
        float inner = qx*mx; inner += qy*my; inner += qz*mz;
        const float d = (sqn - 2.0f*inner) + P.w;            /* ref parenthesization */
        unsigned uu = __float_as_uint(d);
        unsigned e = uu ^ (((unsigned)((int)uu >> 31)) | 0x80000000u);
        unsigned long long key = ((unsigned long long)e << 32) | (unsigned)si[c0 + lane];
        scr[lane] = key;
        __builtin_amdgcn_wave_barrier();
        int r = 0;
#pragma unroll
        for (int t = 0; t < 64; ++t) {
            unsigned long long kt = scr[t];
            r += (kt < key) ? 1 : 0;
        }
        __builtin_amdgcn_wave_barrier();
        if (r < KNN) inc[r] = key;
        __builtin_amdgcn_wave_barrier();
        kthd = key_decode((unsigned)(inc[KNN-1] >> 32));
        M = 1e-3f*(fabsf(kthd) + fabsf(sqn) + 1.0f);
        thr = (kthd - sqn) + M;
    }

    int lo = c0, hi = c0 + 64;
    bool dl = (lo == 0), dr = (hi == NN);

    while (!dl || !dr) {
        if (!dl) {
            const float xb2 = -0.5f*sb[lo-1].x;
            const float dx = qx - xb2;
            if (dx*dx > kthd + M) dl = true;
            else {
                if (cnt > 32) {
                    rank_flush(ovf, inc, scr, cnt, kthd, lane);
                    M = 1e-3f*(fabsf(kthd) + fabsf(sqn) + 1.0f);
                    thr = (kthd - sqn) + M;
                }
                int st = lo - 64; if (st < 0) st = 0;
                const int sI = st + lane;
                const bool valid = sI < lo;
                const float4 P = sb[sI];
                const float sc = fmaf(P.x, qx, fmaf(P.y, qy, fmaf(P.z, qz, P.w)));
                bool push = valid && (sc <= thr);
                unsigned long long mask = __ballot(push);
                if (mask) {
                    if (push) {
                        const float mx = -0.5f*P.x, my = -0.5f*P.y, mz = -0.5f*P.z;
                        float inner = qx*mx; inner += qy*my; inner += qz*mz;
                        const float d = (sqn - 2.0f*inner) + P.w;
                        unsigned uu = __float_as_uint(d);
                        unsigned e = uu ^ (((unsigned)((int)uu >> 31)) | 0x80000000u);
                        unsigned long long key = ((unsigned long long)e << 32) | (unsigned)si[sI];
                        int ofs = (int)__popcll(mask & ((1ull << lane) - 1ull));
                        ovf[cnt + ofs] = key;
                    }
                    cnt += (int)__popcll(mask);
                }
                lo = st;
                dl = (lo == 0);
            }
        }
        if (!dr) {
            const float xb2 = -0.5f*sb[hi].x;
            const float dx = xb2 - qx;
            if (dx*dx > kthd + M) dr = true;
            else {
                if (cnt > 32) {
                    rank_flush(ovf, inc, scr, cnt, kthd, lane);
                    M = 1e-3f*(fabsf(kthd) + fabsf(sqn) + 1.0f);
                    thr = (kthd - sqn) + M;
                }
                int en = hi + 64; if (en > NN) en = NN;
                const int sI = hi + lane;
                const int sa = sI < NN-1 ? sI : NN-1;
                const bool valid = sI < en;
                const float4 P = sb[sa];
                const float sc = fmaf(P.x, qx, fmaf(P.y, qy, fmaf(P.z, qz, P.w)));
                bool push = valid && (sc <= thr);
                unsigned long long mask = __ballot(push);
                if (mask) {
                    if (push) {
                        const float mx = -0.5f*P.x, my = -0.5f*P.y, mz = -0.5f*P.z;
                        float inner = qx*mx; inner += qy*my; inner += qz*mz;
                        const float d = (sqn - 2.0f*inner) + P.w;
                        unsigned uu = __float_as_uint(d);
                        unsigned e = uu ^ (((unsigned)((int)uu >> 31)) | 0x80000000u);
                        unsigned long long key = ((unsigned long long)e << 32) | (unsigned)si[sa];
                        int ofs = (int)__popcll(mask & ((1ull << lane) - 1ull));
                        ovf[cnt + ofs] = key;
                    }
                    cnt += (int)__popcll(mask);
                }
                hi = en;
                dr = (hi == NN);
            }
        }
    }
    rank_flush(ovf, inc, scr, cnt, kthd, lane);

    /* coalesced write at sorted rank; main reads via rankArr */
    if (lane < KNN)
        idx_out[(size_t)s * KNN + lane] = (int)(unsigned)(inc[lane] & 0xFFFFFFFFull);

    /* moments epilogue: lanes 0..19 gather the 20 neighbors, 9 reductions */
    float nx = 0.f, ny = 0.f, nz = 0.f, xx = 0.f, xy = 0.f, xz = 0.f,
          yy = 0.f, yz = 0.f, zz = 0.f;
    if (lane < KNN) {
        int nbr = (int)(unsigned)(inc[lane] & 0xFFFFFFFFull);
        float4 pn = pts4[(b << 12) + nbr];
        nx = -0.5f*pn.x; ny = -0.5f*pn.y; nz = -0.5f*pn.z;
        xx = nx*nx; xy = nx*ny; xz = nx*nz; yy = ny*ny; yz = ny*nz; zz = nz*nz;
    }
#pragma unroll
    for (int off = 32; off > 0; off >>= 1) {
        nx += __shfl_xor(nx, off); ny += __shfl_xor(ny, off); nz += __shfl_xor(nz, off);
        xx += __shfl_xor(xx, off); xy += __shfl_xor(xy, off); xz += __shfl_xor(xz, off);
        yy += __shfl_xor(yy, off); yz += __shfl_xor(yz, off); zz += __shfl_xor(zz, off);
    }
    if (lane == 0) {
        MOM[wv][0] = nx;  MOM[wv][1] = ny;  MOM[wv][2] = nz;
        MOM[wv][3] = qx;  MOM[wv][4] = qy;  MOM[wv][5] = qz;
        MOM[wv][6] = xx;  MOM[wv][7] = xy;  MOM[wv][8] = xz;
        MOM[wv][9] = yy;  MOM[wv][10] = yz; MOM[wv][11] = zz;
        MOM[wv][12] = nx*qx; MOM[wv][13] = nx*qy; MOM[wv][14] = nx*qz;
        MOM[wv][15] = ny*qx; MOM[wv][16] = ny*qy; MOM[wv][17] = ny*qz;
        MOM[wv][18] = nz*qx; MOM[wv][19] = nz*qy; MOM[wv][20] = nz*qz;
        MOM[wv][21] = qx*qx; MOM[wv][22] = qx*qy; MOM[wv][23] = qx*qz;
        MOM[wv][24] = qy*qy; MOM[wv][25] = qy*qz; MOM[wv][26] = qz*qz;
    }
    __syncthreads();
    if (tid < 27)
        atomicAdd(&mstats[(blockIdx.x & (MCOPY-1))*27 + tid],
                  (double)(MOM[0][tid] + MOM[1][tid] + MOM[2][tid] + MOM[3][tid]));
}

/* split fp32 -> bf16 hi (truncate) + bf16 lo (truncated remainder) */
__device__ __forceinline__ void bsplit(float g, short& hi, short& lo) {
    unsigned bits = __float_as_uint(g);
    unsigned hbits = bits & 0xFFFF0000u;
    float rem = g - __uint_as_float(hbits);
    hi = (short)(bits >> 16);
    lo = (short)(__float_as_uint(rem) >> 16);
}

/* ---------------- K5: main pass — shared-leftover-tile split-bf16 MFMA ---------
   Per point: tile1 = rows k=0..15 (24 MFMA). Rows k=16..19 of all 4 points stack
   into one shared 16-row tile (row = p*4+(k-16)), dotted once (24 MFMA).
   120 MFMA/wave vs 192. Combined C-layout: point = quad, k = 16+reg. ---------- */
__global__ __launch_bounds__(256) void main_kernel(const int* __restrict__ idxb,
        const int* __restrict__ rankArr, const float4* __restrict__ pts4,
        const double* __restrict__ ms, const float* __restrict__ W1,
        const float* __restrict__ gamma1, const float* __restrict__ beta1,
        const float* __restrict__ W2,
        float* __restrict__ maxbuf, float* __restrict__ stats2f) {
    __shared__ __align__(16) short Thi[4][32*72];
    __shared__ __align__(16) short Tlo[4][32*72];
    __shared__ float chs[128];
    __shared__ float ab1s[128];
    __shared__ double msd[27];
    const int tid = threadIdx.x;
    const int lane = tid & 63;
    const int wv = __builtin_amdgcn_readfirstlane(tid >> 6);
    const int l15 = lane & 15;
    const int quad = lane >> 4;
    if (tid < 128) chs[tid] = 0.f;
    if (tid < 27) {                                /* sum the 32 mstats copies */
        double t = 0.0;
        for (int c = 0; c < MCOPY; ++c) t += ms[c*27 + tid];
        msd[tid] = t;
    }
    __syncthreads();
    if (tid < 64) {                                /* inline fin1m (bn1 affine) */
        int c = tid;
        double wu[3], wvv[3];
#pragma unroll
        for (int i = 0; i < 3; ++i) {
            wu[i] = (double)W1[c*6 + i];
            wvv[i] = (double)W1[c*6 + 3 + i] - wu[i];
        }
        const double S = (double)SAMPLES;
        double mean = (wu[0]*msd[0] + wu[1]*msd[1] + wu[2]*msd[2]
                     + 20.0*(wvv[0]*msd[3] + wvv[1]*msd[4] + wvv[2]*msd[5])) / S;
        double qM1 = wu[0]*wu[0]*msd[6] + wu[1]*wu[1]*msd[9] + wu[2]*wu[2]*msd[11]
                   + 2.0*(wu[0]*wu[1]*msd[7] + wu[0]*wu[2]*msd[8] + wu[1]*wu[2]*msd[10]);
        double cross = 0.0;
#pragma unroll
        for (int i = 0; i < 3; ++i)
#pragma unroll
            for (int j = 0; j < 3; ++j)
                cross += wu[i] * msd[12 + i*3 + j] * wvv[j];
        double qpp = wvv[0]*wvv[0]*msd[21] + wvv[1]*wvv[1]*msd[24] + wvv[2]*wvv[2]*msd[26]
                   + 2.0*(wvv[0]*wvv[1]*msd[22] + wvv[0]*wvv[2]*msd[23] + wvv[1]*wvv[2]*msd[25]);
        double e2 = (qM1 + 2.0*cross + 20.0*qpp) / S;
        double var = e2 - mean*mean;
        float a = (float)((double)gamma1[c] / sqrt(var + (double)EPSF));
        ab1s[c] = a;
        ab1s[64 + c] = beta1[c] - a * (float)mean;
    }
    __syncthreads();

    bf16x8 whi[8], wlo[8];
#pragma unroll
    for (int t = 0; t < 4; ++t)
#pragma unroll
    for (int f = 0; f < 2; ++f) {
        const int o = 16*t + l15;
        const int c0 = 32*f + quad*8;
        const float4* wr = (const float4*)(W2 + o*64 + c0);
        float4 w0 = wr[0], w1 = wr[1];
        float vals[8] = {w0.x,w0.y,w0.z,w0.w,w1.x,w1.y,w1.z,w1.w};
        bf16x8 h, l;
#pragma unroll
        for (int j = 0; j < 8; ++j) { short hj, lj; bsplit(vals[j], hj, lj); h[j]=hj; l[j]=lj; }
        whi[t*2+f] = h; wlo[t*2+f] = l;
    }

    const float w10 = W1[lane*6+0], w11 = W1[lane*6+1], w12 = W1[lane*6+2];
    const float w13 = W1[lane*6+3], w14 = W1[lane*6+4], w15 = W1[lane*6+5];
    const float a1 = ab1s[lane], b1 = ab1s[64 + lane];
    float ssum[4] = {0.f,0.f,0.f,0.f}, ssq[4] = {0.f,0.f,0.f,0.f};
    float lm[4][4];                                /* deferred tile1 max [point][t] */
    short* thi = &Thi[wv][0];
    short* tlo = &Tlo[wv][0];

    const int pt0 = (blockIdx.x * 4 + wv) * 4;
    const int b = pt0 >> 12;
    const float4* pb = pts4 + ((size_t)b << 12);
    const int* rnk = rankArr + ((size_t)b << 12);

    for (int p = 0; p < 4; ++p) {
        const int pt = pt0 + p;
        const float4 pc = pb[pt & (NN - 1)];
        const float X = -0.5f*pc.x, Y = -0.5f*pc.y, Z = -0.5f*pc.z;
        const float vc = (w13 - w10)*X + (w14 - w11)*Y + (w15 - w12)*Z;
        const int srow = rnk[pt & (NN - 1)];       /* uniform scalar lookup */
        const int* irow = idxb + ((size_t)((b << 12) + srow)) * KNN;
#pragma unroll
        for (int k = 0; k < KNN; ++k) {
            float4 pn = pb[irow[k]];
            float nx = -0.5f*pn.x, ny = -0.5f*pn.y, nz = -0.5f*pn.z;
            float uc = w10*nx + w11*ny + w12*nz;
            float g = a1 * (uc + vc) + b1;
            g = fmaxf(g, SLOPE * g);
            short hj, lj; bsplit(g, hj, lj);
            const int row = (k < 16) ? k : (16 + p*4 + (k - 16));
            thi[row*72 + lane] = hj;
            tlo[row*72 + lane] = lj;
        }
        __builtin_amdgcn_wave_barrier();

        bf16x8 ah1[2], al1[2];
#pragma unroll
        for (int f = 0; f < 2; ++f) {
            const int co = 32*f + quad*8;
            ah1[f] = *(const bf16x8*)&thi[l15*72 + co];
            al1[f] = *(const bf16x8*)&tlo[l15*72 + co];
        }

        f32x4 acc1[4];
#pragma unroll
        for (int t = 0; t < 4; ++t) acc1[t] = (f32x4)0.f;
#pragma unroll
        for (int t = 0; t < 4; ++t) {
#pragma unroll
            for (int f = 0; f < 2; ++f) {
                acc1[t] = __builtin_amdgcn_mfma_f32_16x16x32_bf16(ah1[f], whi[t*2+f], acc1[t], 0,0,0);
                acc1[t] = __builtin_amdgcn_mfma_f32_16x16x32_bf16(al1[f], whi[t*2+f], acc1[t], 0,0,0);
                acc1[t] = __builtin_amdgcn_mfma_f32_16x16x32_bf16(ah1[f], wlo[t*2+f], acc1[t], 0,0,0);
            }
        }
        __builtin_amdgcn_wave_barrier();           /* tile1 reads done before next p */

        /* tile1 epilogue: reduce over rows k=0..15 (quads), defer the write */
#pragma unroll
        for (int t = 0; t < 4; ++t) {
            float m1 = fmaxf(fmaxf(acc1[t][0], acc1[t][1]), fmaxf(acc1[t][2], acc1[t][3]));
            float s1 = acc1[t][0] + acc1[t][1] + acc1[t][2] + acc1[t][3];
            float q1 = acc1[t][0]*acc1[t][0] + acc1[t][1]*acc1[t][1]
                     + acc1[t][2]*acc1[t][2] + acc1[t][3]*acc1[t][3];
            m1 = fmaxf(m1, __shfl_xor(m1, 16)); m1 = fmaxf(m1, __shfl_xor(m1, 32));
            s1 += __shfl_xor(s1, 16); s1 += __shfl_xor(s1, 32);
            q1 += __shfl_xor(q1, 16); q1 += __shfl_xor(q1, 32);
            lm[p][t] = m1;
            ssum[t] += s1; ssq[t] += q1;
        }
    }

    /* combined leftover tile: rows = p*4+(k-16), read once, 24 MFMA */
    {
        bf16x8 ah2[2], al2[2];
#pragma unroll
        for (int f = 0; f < 2; ++f) {
            const int co = 32*f + quad*8;
            ah2[f] = *(const bf16x8*)&thi[(16 + l15)*72 + co];
            al2[f] = *(const bf16x8*)&tlo[(16 + l15)*72 + co];
        }
        f32x4 accC[4];
#pragma unroll
        for (int t = 0; t < 4; ++t) accC[t] = (f32x4)0.f;
#pragma unroll
        for (int t = 0; t < 4; ++t) {
#pragma unroll
            for (int f = 0; f < 2; ++f) {
                accC[t] = __builtin_amdgcn_mfma_f32_16x16x32_bf16(ah2[f], whi[t*2+f], accC[t], 0,0,0);
                accC[t] = __builtin_amdgcn_mfma_f32_16x16x32_bf16(al2[f], whi[t*2+f], accC[t], 0,0,0);
                accC[t] = __builtin_amdgcn_mfma_f32_16x16x32_bf16(ah2[f], wlo[t*2+f], accC[t], 0,0,0);
            }
        }
        /* C row = quad*4+reg -> point = quad, k = 16+reg. Lane finalizes its
           quad's point for channel 16t+l15; quad q writes point pt0+q. */
#pragma unroll
        for (int t = 0; t < 4; ++t) {
            float cm = fmaxf(fmaxf(accC[t][0], accC[t][1]), fmaxf(accC[t][2], accC[t][3]));
            float cs = accC[t][0] + accC[t][1] + accC[t][2] + accC[t][3];
            float cq = accC[t][0]*accC[t][0] + accC[t][1]*accC[t][1]
                     + accC[t][2]*accC[t][2] + accC[t][3]*accC[t][3];
            float lmq = (quad == 0) ? lm[0][t] : (quad == 1) ? lm[1][t]
                      : (quad == 2) ? lm[2][t] : lm[3][t];
            maxbuf[((size_t)(pt0 + quad) << 6) + 16*t + l15] = fmaxf(lmq, cm);
            /* combined sums: reduce over quads (= over the 4 points) */
            cs += __shfl_xor(cs, 16); cs += __shfl_xor(cs, 32);
            cq += __shfl_xor(cq, 16); cq += __shfl_xor(cq, 32);
            ssum[t] += cs; ssq[t] += cq;
        }
    }

    if (quad == 0) {
#pragma unroll
        for (int t = 0; t < 4; ++t) {
            atomicAdd(&chs[16*t + l15], ssum[t]);
            atomicAdd(&chs[64 + 16*t + l15], ssq[t]);
        }
    }
    __syncthreads();
    if (tid < 128)
        atomicAdd(&stats2f[(blockIdx.x & 1)*128 + tid], chs[tid]);
}

/* ---------------- K7: epilogue — fin2 inlined; transpose + bn2 + lrelu --------- */
__global__ __launch_bounds__(256) void out_kernel(const float* __restrict__ maxbuf,
        const float* __restrict__ s2f, const float* __restrict__ gamma2,
        const float* __restrict__ beta2, float* __restrict__ out) {
    __shared__ float t[64][65];
    __shared__ float ab2s[128];
    const int tid = threadIdx.x;
    if (tid < 64) {                                /* inline fin2 */
        int o = tid;
        double sum = (double)s2f[o] + (double)s2f[128 + o];
        double sq  = (double)s2f[64 + o] + (double)s2f[192 + o];
        double cnt = (double)SAMPLES;
        double mean = sum / cnt;
        double var  = sq / cnt - mean*mean;
        float a = (float)((double)gamma2[o] / sqrt(var + (double)EPSF));
        ab2s[o] = a;
        ab2s[64 + o] = beta2[o] - a * (float)mean;
    }
    const int b = blockIdx.x >> 6;
    const int n0 = (blockIdx.x & 63) << 6;
#pragma unroll
    for (int i = 0; i < 16; ++i) {
        int r = (tid >> 6) + i*4;
        int c = tid & 63;
        t[r][c] = maxbuf[(((size_t)((b << 12) + n0 + r)) << 6) + c];
    }
    __syncthreads();
#pragma unroll
    for (int i = 0; i < 16; ++i) {
        int o = (tid >> 6) + i*4;
        int nn = tid & 63;
        float a = ab2s[o], bb = ab2s[64 + o];
        float h = a * t[nn][o] + bb;
        out[(((size_t)(b*64 + o)) << 12) + n0 + nn] = h >= 0.f ? h : SLOPE*h;
    }
}

extern "C" void kernel_launch(void* const* d_in, const int* in_sizes, int n_in,
                              void* d_out, int out_size, void* d_ws, size_t ws_size,
                              hipStream_t stream) {
    const float* x      = (const float*)d_in[0];
    const float* W1     = (const float*)d_in[1];
    const float* gamma1 = (const float*)d_in[2];
    const float* beta1  = (const float*)d_in[3];
    const float* W2     = (const float*)d_in[4];
    const float* gamma2 = (const float*)d_in[5];
    const float* beta2  = (const float*)d_in[6];
    float* out = (float*)d_out;

    char* ws = (char*)d_ws;
    int*    idxb    = (int*)   (ws + 0);           /* 2,621,440 B (sorted order) */
    float4* pts4    = (float4*)(ws + 2621440);     /* 512 KB */
    float4* sp4     = (float4*)(ws + 3145728);     /* 512 KB sorted pts */
    int*    sidx    = (int*)   (ws + 3670016);     /* 128 KB sorted->orig */
    int*    rankArr = (int*)   (ws + 3801088);     /* 128 KB orig->sorted */
    float*  maxbuf  = (float*) (ws + 19398656);    /* 8,388,608 B, (b,n,o) */
    double* mstats  = (double*)(ws + 27787264);    /* 32x27 doubles = 6912 B */
    float*  stats2f = (float*) (ws + 27794176);    /* 2x128 floats = 1024 B */
    double* zreg    = (double*)(ws + 27787264);    /* zero region: 992 doubles */

    sort_kernel <<<8, 1024, 0, stream>>>(x, pts4, sp4, sidx, rankArr, zreg);
    knn_kernel  <<<8192, 256, 0, stream>>>(pts4, sp4, sidx, idxb, mstats);
    main_kernel <<<2048, 256, 0, stream>>>(idxb, rankArr, pts4, mstats, W1, gamma1,
                                           beta1, W2, maxbuf, stats2f);
    out_kernel  <<<512, 256, 0, stream>>>(maxbuf, stats2f, gamma2, beta2, out);
}

// Round 14
// 258.013 us; speedup vs baseline: 1.6897x; 1.0017x over previous
//
#include <hip/hip_runtime.h>
#include <hip/hip_bf16.h>
#include <math.h>

#define BB 8
#define NN 4096
#define KNN 20
#define CH 64
#define SAMPLES (BB*NN*KNN)   /* 655360 */
#define EPSF 1e-5f
#define SLOPE 0.2f
#define MCOPY 32              /* mstats copies to spread atomic contention */

typedef float f32x4 __attribute__((ext_vector_type(4)));
typedef short bf16x8 __attribute__((ext_vector_type(8)));

/* decode order-preserving uint back to float */
__device__ __forceinline__ float key_decode(unsigned e) {
    return __uint_as_float((e & 0x80000000u) ? (e ^ 0x80000000u) : ~e);
}

/* rank-select flush: merge ovf[0..cnt) + inc[0..19] -> new exact top-20 in inc. */
__device__ __forceinline__ void rank_flush(unsigned long long* ovf,
                                           unsigned long long* inc,
                                           unsigned long long* scr,
                                           int& cnt, float& kthd, int lane) {
    while (cnt > 0) {
        int take = cnt < 44 ? cnt : 44;
        unsigned long long key;
        if (lane < take)      key = ovf[cnt - take + lane];
        else if (lane >= 44)  key = inc[lane - 44];
        else                  key = ~0ull;
        scr[lane] = key;
        __builtin_amdgcn_wave_barrier();
        int r = 0;
#pragma unroll
        for (int t = 0; t < 64; ++t) {
            unsigned long long kt = scr[t];       /* uniform addr -> broadcast */
            r += (kt < key) ? 1 : 0;
        }
        __builtin_amdgcn_wave_barrier();
        if (r < KNN) inc[r] = key;                /* padding ranks land >= 20 */
        __builtin_amdgcn_wave_barrier();
        kthd = key_decode((unsigned)(inc[KNN-1] >> 32));
        cnt -= take;
    }
}

/* ---------------- K0: per-batch: build pts4 + bitonic sort by x + zero stats --- */
__global__ __launch_bounds__(1024) void sort_kernel(const float* __restrict__ x,
        float4* __restrict__ pts4, float4* __restrict__ sp4, int* __restrict__ sidx,
        int* __restrict__ rankArr, double* __restrict__ zreg) {
#pragma clang fp contract(off)
    __shared__ unsigned long long S[NN];                     /* 32 KB */
    const int tid = threadIdx.x;
    const int b = blockIdx.x;
    if (b == 0 && tid < 992) zreg[tid] = 0.0;     /* mstats(864d) + stats2f(128d) */
    const float* xb = x + (size_t)b * 3 * NN;
    for (int i = tid; i < NN; i += 1024) {
        float mx = xb[i], my = xb[NN + i], mz = xb[2*NN + i];
        float sq = mx*mx; sq += my*my; sq += mz*mz;          /* ref summation order */
        pts4[(b << 12) + i] = make_float4(-2.0f*mx, -2.0f*my, -2.0f*mz, sq);
        unsigned uu = __float_as_uint(mx);
        unsigned e = uu ^ (((unsigned)((int)uu >> 31)) | 0x80000000u);
        S[i] = ((unsigned long long)e << 32) | (unsigned)i;
    }
    __syncthreads();
    for (int k = 2; k <= NN; k <<= 1) {
        for (int j = k >> 1; j > 0; j >>= 1) {
#pragma unroll
            for (int tt = 0; tt < 2; ++tt) {
                int t = tid + tt*1024;            /* 2048 pairs */
                int i = ((t & ~(j - 1)) << 1) | (t & (j - 1));
                int h = i | j;
                unsigned long long a = S[i], c = S[h];
                bool up = ((i & k) == 0);
                if ((a > c) == up) { S[i] = c; S[h] = a; }
            }
            __syncthreads();
        }
    }
    for (int s = tid; s < NN; s += 1024) {
        int oi = (int)(unsigned)(S[s] & 0xFFFFFFFFu);
        float mx = xb[oi], my = xb[NN + oi], mz = xb[2*NN + oi];  /* recompute: no RAW */
        float sq = mx*mx; sq += my*my; sq += mz*mz;
        sp4[(b << 12) + s] = make_float4(-2.0f*mx, -2.0f*my, -2.0f*mz, sq);
        sidx[(b << 12) + s] = oi;
        rankArr[(b << 12) + oi] = s;
    }
}

/* ---------------- K1: exact KNN — pipelined sorted sweep + moments epilogue.
   Both sides' chunk data AND boundary x are prefetched one iteration ahead,
   breaking the serial load->check->load chain. idx_out at sorted rank. -------- */
__global__ __launch_bounds__(256) void knn_kernel(const float4* __restrict__ pts4,
        const float4* __restrict__ sp4, const int* __restrict__ sidx,
        int* __restrict__ idx_out, double* __restrict__ mstats) {
#pragma clang fp contract(off)
    __shared__ unsigned long long OVF[4][160];               /* 5 KB   */
    __shared__ unsigned long long INC[4][24];
    __shared__ unsigned long long SCR[4][64];
    __shared__ float MOM[4][27];
    const int tid = threadIdx.x;
    const int lane = tid & 63;
    const int wv = __builtin_amdgcn_readfirstlane(tid >> 6);
    const int s = blockIdx.x * 4 + wv;                       /* sorted-rank query */
    const int b = s >> 12;
    const int ss = s & (NN - 1);
    const float4* sb = sp4 + ((size_t)b << 12);
    const int* si = sidx + ((size_t)b << 12);
    unsigned long long* ovf = &OVF[wv][0];
    unsigned long long* inc = &INC[wv][0];
    unsigned long long* scr = &SCR[wv][0];

    const float4 Qc = sb[ss];
    const float qx = -0.5f*Qc.x, qy = -0.5f*Qc.y, qz = -0.5f*Qc.z; /* exact coords */
    const float sqn = Qc.w;
    int c0 = ss - 32; c0 = c0 < 0 ? 0 : (c0 > NN-64 ? NN-64 : c0);
    float kthd, thr, M;
    int cnt = 0;

    /* prefill: exact d for the 64 nearest-in-x, rank-select directly */
    {
        const float4 P = sb[c0 + lane];
        const float mx = -0.5f*P.x, my = -0.5f*P.y, mz = -0.5f*P.z;
        float inner = qx*mx; inner += qy*my; inner += qz*mz;
        const float d = (sqn - 2.0f*inner) + P.w;            /* ref parenthesization */
        unsigned uu = __float_as_uint(d);
        unsigned e = uu ^ (((unsigned)((int)uu >> 31)) | 0x80000000u);
        unsigned long long key = ((unsigned long long)e << 32) | (unsigned)si[c0 + lane];
        scr[lane] = key;
        __builtin_amdgcn_wave_barrier();
        int r = 0;
#pragma unroll
        for (int t = 0; t < 64; ++t) {
            unsigned long long kt = scr[t];
            r += (kt < key) ? 1 : 0;
        }
        __builtin_amdgcn_wave_barrier();
        if (r < KNN) inc[r] = key;
        __builtin_amdgcn_wave_barrier();
        kthd = key_decode((unsigned)(inc[KNN-1] >> 32));
        M = 1e-3f*(fabsf(kthd) + fabsf(sqn) + 1.0f);
        thr = (kthd - sqn) + M;
    }

    int lo = c0, hi = c0 + 64;
    bool dl = (lo == 0), dr = (hi == NN);

    /* prime the pipeline: chunk data + boundary x for each live side */
    float4 PL, PR;
    float xL = 0.f, xR = 0.f;
    if (!dl) {
        int st = lo - 64; st = st < 0 ? 0 : st;
        PL = sb[st + lane];                        /* st+63 <= lo-1 < NN */
        xL = sb[lo - 1].x;
    }
    if (!dr) {
        int sI = hi + lane;
        PR = sb[sI < NN-1 ? sI : NN-1];
        xR = sb[hi].x;
    }

    while (!dl || !dr) {
        bool goL = false, goR = false;
        if (!dl) {                                 /* checks on PREFETCHED x: no stall */
            const float dx = qx - (-0.5f*xL);
            goL = (dx*dx <= kthd + M);
            if (!goL) dl = true;
        }
        if (!dr) {
            const float dx = (-0.5f*xR) - qx;
            goR = (dx*dx <= kthd + M);
            if (!goR) dr = true;
        }
        const int stL = (lo - 64) < 0 ? 0 : (lo - 64);
        const int enR = (hi + 64) > NN ? NN : (hi + 64);

        /* issue next-iteration prefetches before doing any work */
        float4 PLn = PL, PRn = PR;
        float xLn = 0.f, xRn = 0.f;
        if (goL && stL > 0) {
            int st2 = stL - 64; st2 = st2 < 0 ? 0 : st2;
            PLn = sb[st2 + lane];
            xLn = sb[stL - 1].x;
        }
        if (goR && enR < NN) {
            int sI = enR + lane;
            PRn = sb[sI < NN-1 ? sI : NN-1];
            xRn = sb[enR].x;
        }

        if (cnt > 32) {                            /* LDS flush overlaps the loads */
            rank_flush(ovf, inc, scr, cnt, kthd, lane);
            M = 1e-3f*(fabsf(kthd) + fabsf(sqn) + 1.0f);
            thr = (kthd - sqn) + M;
        }

        if (goL) {
            const int sI = stL + lane;
            const bool valid = sI < lo;
            const float sc = fmaf(PL.x, qx, fmaf(PL.y, qy, fmaf(PL.z, qz, PL.w)));
            bool push = valid && (sc <= thr);
            unsigned long long mask = __ballot(push);
            if (mask) {
                if (push) {
                    const float mx = -0.5f*PL.x, my = -0.5f*PL.y, mz = -0.5f*PL.z;
                    float inner = qx*mx; inner += qy*my; inner += qz*mz;
                    const float d = (sqn - 2.0f*inner) + PL.w;
                    unsigned uu = __float_as_uint(d);
                    unsigned e = uu ^ (((unsigned)((int)uu >> 31)) | 0x80000000u);
                    unsigned long long key = ((unsigned long long)e << 32) | (unsigned)si[sI];
                    int ofs = (int)__popcll(mask & ((1ull << lane) - 1ull));
                    ovf[cnt + ofs] = key;
                }
                cnt += (int)__popcll(mask);
            }
            lo = stL;
            dl = (lo == 0);
            PL = PLn; xL = xLn;
        }
        if (goR) {
            const int sI = hi + lane;
            const int sa = sI < NN-1 ? sI : NN-1;
            const bool valid = sI < enR;
            const float sc = fmaf(PR.x, qx, fmaf(PR.y, qy, fmaf(PR.z, qz, PR.w)));
            bool push = valid && (sc <= thr);
            unsigned long long mask = __ballot(push);
            if (mask) {
                if (push) {
                    const float mx = -0.5f*PR.x, my = -0.5f*PR.y, mz = -0.5f*PR.z;
                    float inner = qx*mx; inner += qy*my; inner += qz*mz;
                    const float d = (sqn - 2.0f*inner) + PR.w;
                    unsigned uu = __float_as_uint(d);
                    unsigned e = uu ^ (((unsigned)((int)uu >> 31)) | 0x80000000u);
                    unsigned long long key = ((unsigned long long)e << 32) | (unsigned)si[sa];
                    int ofs = (int)__popcll(mask & ((1ull << lane) - 1ull));
                    ovf[cnt + ofs] = key;
                }
                cnt += (int)__popcll(mask);
            }
            hi = enR;
            dr = (hi == NN);
            PR = PRn; xR = xRn;
        }
    }
    rank_flush(ovf, inc, scr, cnt, kthd, lane);

    /* coalesced write at sorted rank; main reads via rankArr */
    if (lane < KNN)
        idx_out[(size_t)s * KNN + lane] = (int)(unsigned)(inc[lane] & 0xFFFFFFFFull);

    /* moments epilogue: lanes 0..19 gather the 20 neighbors, 9 reductions */
    float nx = 0.f, ny = 0.f, nz = 0.f, xx = 0.f, xy = 0.f, xz = 0.f,
          yy = 0.f, yz = 0.f, zz = 0.f;
    if (lane < KNN) {
        int nbr = (int)(unsigned)(inc[lane] & 0xFFFFFFFFull);
        float4 pn = pts4[(b << 12) + nbr];
        nx = -0.5f*pn.x; ny = -0.5f*pn.y; nz = -0.5f*pn.z;
        xx = nx*nx; xy = nx*ny; xz = nx*nz; yy = ny*ny; yz = ny*nz; zz = nz*nz;
    }
#pragma unroll
    for (int off = 32; off > 0; off >>= 1) {
        nx += __shfl_xor(nx, off); ny += __shfl_xor(ny, off); nz += __shfl_xor(nz, off);
        xx += __shfl_xor(xx, off); xy += __shfl_xor(xy, off); xz += __shfl_xor(xz, off);
        yy += __shfl_xor(yy, off); yz += __shfl_xor(yz, off); zz += __shfl_xor(zz, off);
    }
    if (lane == 0) {
        MOM[wv][0] = nx;  MOM[wv][1] = ny;  MOM[wv][2] = nz;
        MOM[wv][3] = qx;  MOM[wv][4] = qy;  MOM[wv][5] = qz;
        MOM[wv][6] = xx;  MOM[wv][7] = xy;  MOM[wv][8] = xz;
        MOM[wv][9] = yy;  MOM[wv][10] = yz; MOM[wv][11] = zz;
        MOM[wv][12] = nx*qx; MOM[wv][13] = nx*qy; MOM[wv][14] = nx*qz;
        MOM[wv][15] = ny*qx; MOM[wv][16] = ny*qy; MOM[wv][17] = ny*qz;
        MOM[wv][18] = nz*qx; MOM[wv][19] = nz*qy; MOM[wv][20] = nz*qz;
        MOM[wv][21] = qx*qx; MOM[wv][22] = qx*qy; MOM[wv][23] = qx*qz;
        MOM[wv][24] = qy*qy; MOM[wv][25] = qy*qz; MOM[wv][26] = qz*qz;
    }
    __syncthreads();
    if (tid < 27)
        atomicAdd(&mstats[(blockIdx.x & (MCOPY-1))*27 + tid],
                  (double)(MOM[0][tid] + MOM[1][tid] + MOM[2][tid] + MOM[3][tid]));
}

/* split fp32 -> bf16 hi (truncate) + bf16 lo (truncated remainder) */
__device__ __forceinline__ void bsplit(float g, short& hi, short& lo) {
    unsigned bits = __float_as_uint(g);
    unsigned hbits = bits & 0xFFFF0000u;
    float rem = g - __uint_as_float(hbits);
    hi = (short)(bits >> 16);
    lo = (short)(__float_as_uint(rem) >> 16);
}

/* ---------------- K5: main pass — shared-leftover-tile split-bf16 MFMA --------- */
__global__ __launch_bounds__(256) void main_kernel(const int* __restrict__ idxb,
        const int* __restrict__ rankArr, const float4* __restrict__ pts4,
        const double* __restrict__ ms, const float* __restrict__ W1,
        const float* __restrict__ gamma1, const float* __restrict__ beta1,
        const float* __restrict__ W2,
        float* __restrict__ maxbuf, float* __restrict__ stats2f) {
    __shared__ __align__(16) short Thi[4][32*72];
    __shared__ __align__(16) short Tlo[4][32*72];
    __shared__ float chs[128];
    __shared__ float ab1s[128];
    __shared__ double msd[27];
    const int tid = threadIdx.x;
    const int lane = tid & 63;
    const int wv = __builtin_amdgcn_readfirstlane(tid >> 6);
    const int l15 = lane & 15;
    const int quad = lane >> 4;
    if (tid < 128) chs[tid] = 0.f;
    if (tid < 27) {                                /* sum the 32 mstats copies */
        double t = 0.0;
        for (int c = 0; c < MCOPY; ++c) t += ms[c*27 + tid];
        msd[tid] = t;
    }
    __syncthreads();
    if (tid < 64) {                                /* inline fin1m (bn1 affine) */
        int c = tid;
        double wu[3], wvv[3];
#pragma unroll
        for (int i = 0; i < 3; ++i) {
            wu[i] = (double)W1[c*6 + i];
            wvv[i] = (double)W1[c*6 + 3 + i] - wu[i];
        }
        const double S = (double)SAMPLES;
        double mean = (wu[0]*msd[0] + wu[1]*msd[1] + wu[2]*msd[2]
                     + 20.0*(wvv[0]*msd[3] + wvv[1]*msd[4] + wvv[2]*msd[5])) / S;
        double qM1 = wu[0]*wu[0]*msd[6] + wu[1]*wu[1]*msd[9] + wu[2]*wu[2]*msd[11]
                   + 2.0*(wu[0]*wu[1]*msd[7] + wu[0]*wu[2]*msd[8] + wu[1]*wu[2]*msd[10]);
        double cross = 0.0;
#pragma unroll
        for (int i = 0; i < 3; ++i)
#pragma unroll
            for (int j = 0; j < 3; ++j)
                cross += wu[i] * msd[12 + i*3 + j] * wvv[j];
        double qpp = wvv[0]*wvv[0]*msd[21] + wvv[1]*wvv[1]*msd[24] + wvv[2]*wvv[2]*msd[26]
                   + 2.0*(wvv[0]*wvv[1]*msd[22] + wvv[0]*wvv[2]*msd[23] + wvv[1]*wvv[2]*msd[25]);
        double e2 = (qM1 + 2.0*cross + 20.0*qpp) / S;
        double var = e2 - mean*mean;
        float a = (float)((double)gamma1[c] / sqrt(var + (double)EPSF));
        ab1s[c] = a;
        ab1s[64 + c] = beta1[c] - a * (float)mean;
    }
    __syncthreads();

    bf16x8 whi[8], wlo[8];
#pragma unroll
    for (int t = 0; t < 4; ++t)
#pragma unroll
    for (int f = 0; f < 2; ++f) {
        const int o = 16*t + l15;
        const int c0 = 32*f + quad*8;
        const float4* wr = (const float4*)(W2 + o*64 + c0);
        float4 w0 = wr[0], w1 = wr[1];
        float vals[8] = {w0.x,w0.y,w0.z,w0.w,w1.x,w1.y,w1.z,w1.w};
        bf16x8 h, l;
#pragma unroll
        for (int j = 0; j < 8; ++j) { short hj, lj; bsplit(vals[j], hj, lj); h[j]=hj; l[j]=lj; }
        whi[t*2+f] = h; wlo[t*2+f] = l;
    }

    const float w10 = W1[lane*6+0], w11 = W1[lane*6+1], w12 = W1[lane*6+2];
    const float w13 = W1[lane*6+3], w14 = W1[lane*6+4], w15 = W1[lane*6+5];
    const float a1 = ab1s[lane], b1 = ab1s[64 + lane];
    float ssum[4] = {0.f,0.f,0.f,0.f}, ssq[4] = {0.f,0.f,0.f,0.f};
    float lm[4][4];                                /* deferred tile1 max [point][t] */
    short* thi = &Thi[wv][0];
    short* tlo = &Tlo[wv][0];

    const int pt0 = (blockIdx.x * 4 + wv) * 4;
    const int b = pt0 >> 12;
    const float4* pb = pts4 + ((size_t)b << 12);
    const int* rnk = rankArr + ((size_t)b << 12);

    for (int p = 0; p < 4; ++p) {
        const int pt = pt0 + p;
        const float4 pc = pb[pt & (NN - 1)];
        const float X = -0.5f*pc.x, Y = -0.5f*pc.y, Z = -0.5f*pc.z;
        const float vc = (w13 - w10)*X + (w14 - w11)*Y + (w15 - w12)*Z;
        const int srow = rnk[pt & (NN - 1)];       /* uniform scalar lookup */
        const int* irow = idxb + ((size_t)((b << 12) + srow)) * KNN;
#pragma unroll
        for (int k = 0; k < KNN; ++k) {
            float4 pn = pb[irow[k]];
            float nx = -0.5f*pn.x, ny = -0.5f*pn.y, nz = -0.5f*pn.z;
            float uc = w10*nx + w11*ny + w12*nz;
            float g = a1 * (uc + vc) + b1;
            g = fmaxf(g, SLOPE * g);
            short hj, lj; bsplit(g, hj, lj);
            const int row = (k < 16) ? k : (16 + p*4 + (k - 16));
            thi[row*72 + lane] = hj;
            tlo[row*72 + lane] = lj;
        }
        __builtin_amdgcn_wave_barrier();

        bf16x8 ah1[2], al1[2];
#pragma unroll
        for (int f = 0; f < 2; ++f) {
            const int co = 32*f + quad*8;
            ah1[f] = *(const bf16x8*)&thi[l15*72 + co];
            al1[f] = *(const bf16x8*)&tlo[l15*72 + co];
        }

        f32x4 acc1[4];
#pragma unroll
        for (int t = 0; t < 4; ++t) acc1[t] = (f32x4)0.f;
#pragma unroll
        for (int t = 0; t < 4; ++t) {
#pragma unroll
            for (int f = 0; f < 2; ++f) {
                acc1[t] = __builtin_amdgcn_mfma_f32_16x16x32_bf16(ah1[f], whi[t*2+f], acc1[t], 0,0,0);
                acc1[t] = __builtin_amdgcn_mfma_f32_16x16x32_bf16(al1[f], whi[t*2+f], acc1[t], 0,0,0);
                acc1[t] = __builtin_amdgcn_mfma_f32_16x16x32_bf16(ah1[f], wlo[t*2+f], acc1[t], 0,0,0);
            }
        }
        __builtin_amdgcn_wave_barrier();           /* tile1 reads done before next p */

        /* tile1 epilogue: reduce over rows k=0..15 (quads), defer the write */
#pragma unroll
        for (int t = 0; t < 4; ++t) {
            float m1 = fmaxf(fmaxf(acc1[t][0], acc1[t][1]), fmaxf(acc1[t][2], acc1[t][3]));
            float s1 = acc1[t][0] + acc1[t][1] + acc1[t][2] + acc1[t][3];
            float q1 = acc1[t][0]*acc1[t][0] + acc1[t][1]*acc1[t][1]
                     + acc1[t][2]*acc1[t][2] + acc1[t][3]*acc1[t][3];
            m1 = fmaxf(m1, __shfl_xor(m1, 16)); m1 = fmaxf(m1, __shfl_xor(m1, 32));
            s1 += __shfl_xor(s1, 16); s1 += __shfl_xor(s1, 32);
            q1 += __shfl_xor(q1, 16); q1 += __shfl_xor(q1, 32);
            lm[p][t] = m1;
            ssum[t] += s1; ssq[t] += q1;
        }
    }

    /* combined leftover tile: rows = p*4+(k-16), read once, 24 MFMA */
    {
        bf16x8 ah2[2], al2[2];
#pragma unroll
        for (int f = 0; f < 2; ++f) {
            const int co = 32*f + quad*8;
            ah2[f] = *(const bf16x8*)&thi[(16 + l15)*72 + co];
            al2[f] = *(const bf16x8*)&tlo[(16 + l15)*72 + co];
        }
        f32x4 accC[4];
#pragma unroll
        for (int t = 0; t < 4; ++t) accC[t] = (f32x4)0.f;
#pragma unroll
        for (int t = 0; t < 4; ++t) {
#pragma unroll
            for (int f = 0; f < 2; ++f) {
                accC[t] = __builtin_amdgcn_mfma_f32_16x16x32_bf16(ah2[f], whi[t*2+f], accC[t], 0,0,0);
                accC[t] = __builtin_amdgcn_mfma_f32_16x16x32_bf16(al2[f], whi[t*2+f], accC[t], 0,0,0);
                accC[t] = __builtin_amdgcn_mfma_f32_16x16x32_bf16(ah2[f], wlo[t*2+f], accC[t], 0,0,0);
            }
        }
        /* C row = quad*4+reg -> point = quad, k = 16+reg. */
#pragma unroll
        for (int t = 0; t < 4; ++t) {
            float cm = fmaxf(fmaxf(accC[t][0], accC[t][1]), fmaxf(accC[t][2], accC[t][3]));
            float cs = accC[t][0] + accC[t][1] + accC[t][2] + accC[t][3];
            float cq = accC[t][0]*accC[t][0] + accC[t][1]*accC[t][1]
                     + accC[t][2]*accC[t][2] + accC[t][3]*accC[t][3];
            float lmq = (quad == 0) ? lm[0][t] : (quad == 1) ? lm[1][t]
                      : (quad == 2) ? lm[2][t] : lm[3][t];
            maxbuf[((size_t)(pt0 + quad) << 6) + 16*t + l15] = fmaxf(lmq, cm);
            cs += __shfl_xor(cs, 16); cs += __shfl_xor(cs, 32);
            cq += __shfl_xor(cq, 16); cq += __shfl_xor(cq, 32);
            ssum[t] += cs; ssq[t] += cq;
        }
    }

    if (quad == 0) {
#pragma unroll
        for (int t = 0; t < 4; ++t) {
            atomicAdd(&chs[16*t + l15], ssum[t]);
            atomicAdd(&chs[64 + 16*t + l15], ssq[t]);
        }
    }
    __syncthreads();
    if (tid < 128)
        atomicAdd(&stats2f[(blockIdx.x & 1)*128 + tid], chs[tid]);
}

/* ---------------- K7: epilogue — fin2 inlined; transpose + bn2 + lrelu --------- */
__global__ __launch_bounds__(256) void out_kernel(const float* __restrict__ maxbuf,
        const float* __restrict__ s2f, const float* __restrict__ gamma2,
        const float* __restrict__ beta2, float* __restrict__ out) {
    __shared__ float t[64][65];
    __shared__ float ab2s[128];
    const int tid = threadIdx.x;
    if (tid < 64) {                                /* inline fin2 */
        int o = tid;
        double sum = (double)s2f[o] + (double)s2f[128 + o];
        double sq  = (double)s2f[64 + o] + (double)s2f[192 + o];
        double cnt = (double)SAMPLES;
        double mean = sum / cnt;
        double var  = sq / cnt - mean*mean;
        float a = (float)((double)gamma2[o] / sqrt(var + (double)EPSF));
        ab2s[o] = a;
        ab2s[64 + o] = beta2[o] - a * (float)mean;
    }
    const int b = blockIdx.x >> 6;
    const int n0 = (blockIdx.x & 63) << 6;
#pragma unroll
    for (int i = 0; i < 16; ++i) {
        int r = (tid >> 6) + i*4;
        int c = tid & 63;
        t[r][c] = maxbuf[(((size_t)((b << 12) + n0 + r)) << 6) + c];
    }
    __syncthreads();
#pragma unroll
    for (int i = 0; i < 16; ++i) {
        int o = (tid >> 6) + i*4;
        int nn = tid & 63;
        float a = ab2s[o], bb = ab2s[64 + o];
        float h = a * t[nn][o] + bb;
        out[(((size_t)(b*64 + o)) << 12) + n0 + nn] = h >= 0.f ? h : SLOPE*h;
    }
}

extern "C" void kernel_launch(void* const* d_in, const int* in_sizes, int n_in,
                              void* d_out, int out_size, void* d_ws, size_t ws_size,
                              hipStream_t stream) {
    const float* x      = (const float*)d_in[0];
    const float* W1     = (const float*)d_in[1];
    const float* gamma1 = (const float*)d_in[2];
    const float* beta1  = (const float*)d_in[3];
    const float* W2     = (const float*)d_in[4];
    const float* gamma2 = (const float*)d_in[5];
    const float* beta2  = (const float*)d_in[6];
    float* out = (float*)d_out;

    char* ws = (char*)d_ws;
    int*    idxb    = (int*)   (ws + 0);           /* 2,621,440 B (sorted order) */
    float4* pts4    = (float4*)(ws + 2621440);     /* 512 KB */
    float4* sp4     = (float4*)(ws + 3145728);     /* 512 KB sorted pts */
    int*    sidx    = (int*)   (ws + 3670016);     /* 128 KB sorted->orig */
    int*    rankArr = (int*)   (ws + 3801088);     /* 128 KB orig->sorted */
    float*  maxbuf  = (float*) (ws + 19398656);    /* 8,388,608 B, (b,n,o) */
    double* mstats  = (double*)(ws + 27787264);    /* 32x27 doubles = 6912 B */
    float*  stats2f = (float*) (ws + 27794176);    /* 2x128 floats = 1024 B */
    double* zreg    = (double*)(ws + 27787264);    /* zero region: 992 doubles */

    sort_kernel <<<8, 1024, 0, stream>>>(x, pts4, sp4, sidx, rankArr, zreg);
    knn_kernel  <<<8192, 256, 0, stream>>>(pts4, sp4, sidx, idxb, mstats);
    main_kernel <<<2048, 256, 0, stream>>>(idxb, rankArr, pts4, mstats, W1, gamma1,
                                           beta1, W2, maxbuf, stats2f);
    out_kernel  <<<512, 256, 0, stream>>>(maxbuf, stats2f, gamma2, beta2, out);
}